// Round 1
// baseline (3587.212 us; speedup 1.0000x reference)
//
#include <hip/hip_runtime.h>
#include <cstdint>
#include <cstddef>

#define HWN 16384   // H*W
#define NP1 1024    // pooled positions

// ---------------------------------------------------------------------------
// K1: qkv[b][o][p] = sum_c qkv_w[o][c] * x[b][c][p] + qkv_b[o]
// grid (256 p-tiles, 6 o-tiles, 2 b), 256 thr, 64x64 tile, K-chunk 32
// ---------------------------------------------------------------------------
__global__ __launch_bounds__(256) void k_qkv(
    const float* __restrict__ x, const float* __restrict__ w,
    const float* __restrict__ bias, float* __restrict__ qkv) {
  int pt = blockIdx.x * 64, ot = blockIdx.y * 64, bb = blockIdx.z;
  int tid = threadIdx.x;
  __shared__ float Wsm[64][33];
  __shared__ float Xsm[32][65];
  float acc[4][4] = {};
  const float* xb = x + (size_t)bb * 256 * HWN;
  for (int c0 = 0; c0 < 256; c0 += 32) {
    for (int l = tid; l < 64 * 32; l += 256) {
      int oo = l >> 5, cc = l & 31;
      Wsm[oo][cc] = w[(size_t)(ot + oo) * 256 + c0 + cc];
    }
    for (int l = tid; l < 32 * 64; l += 256) {
      int cc = l >> 6, pp = l & 63;
      Xsm[cc][pp] = xb[(size_t)(c0 + cc) * HWN + pt + pp];
    }
    __syncthreads();
#pragma unroll
    for (int kk = 0; kk < 32; ++kk) {
      float wv[4], xv[4];
#pragma unroll
      for (int r = 0; r < 4; ++r) wv[r] = Wsm[(tid >> 4) * 4 + r][kk];
#pragma unroll
      for (int s = 0; s < 4; ++s) xv[s] = Xsm[kk][(tid & 15) * 4 + s];
#pragma unroll
      for (int r = 0; r < 4; ++r)
#pragma unroll
        for (int s = 0; s < 4; ++s) acc[r][s] += wv[r] * xv[s];
    }
    __syncthreads();
  }
#pragma unroll
  for (int r = 0; r < 4; ++r) {
    int oo = ot + (tid >> 4) * 4 + r;
    float bv = bias[oo];
#pragma unroll
    for (int s = 0; s < 4; ++s) {
      int pp = pt + (tid & 15) * 4 + s;
      qkv[((size_t)bb * 384 + oo) * HWN + pp] = acc[r][s] + bv;
    }
  }
}

// ---------------------------------------------------------------------------
// K2: 4x4 average pool of Q (ch 0..63) and K (ch 64..127) -> q,k [bg][32][1024]
// ---------------------------------------------------------------------------
__global__ __launch_bounds__(256) void k_pool(
    const float* __restrict__ qkv, float* __restrict__ qp, float* __restrict__ kp) {
  int idx = blockIdx.x * 256 + threadIdx.x;  // 131072 total
  int i1 = idx & 1023, cc = (idx >> 10) & 31, bg = idx >> 15;
  int b = bg >> 1, g = bg & 1;
  int h1 = i1 >> 5, w1 = i1 & 31;
  const float* baseq = qkv + ((size_t)b * 384 + g * 32 + cc) * HWN;
  const float* basek = qkv + ((size_t)b * 384 + 64 + g * 32 + cc) * HWN;
  float sq = 0.f, sk = 0.f;
#pragma unroll
  for (int sh = 0; sh < 4; ++sh) {
    int row = (h1 * 4 + sh) * 128 + w1 * 4;
#pragma unroll
    for (int sw = 0; sw < 4; ++sw) { sq += baseq[row + sw]; sk += basek[row + sw]; }
  }
  qp[idx] = sq * 0.0625f;
  kp[idx] = sk * 0.0625f;
}

// ---------------------------------------------------------------------------
// K3: A_m column softmax -> Tt[bg][j][i] = 0.5*(delta(i,j) - A_m[i][j])
// one block per (column j, bg); 256 thr, 4 rows each
// ---------------------------------------------------------------------------
__global__ __launch_bounds__(256) void k_amT(
    const float* __restrict__ qp, const float* __restrict__ kp, float* __restrict__ Tt) {
  int j = blockIdx.x, bg = blockIdx.y, tid = threadIdx.x;
  __shared__ float qj[32];
  __shared__ float sred[8];
  if (tid < 32) qj[tid] = qp[((size_t)bg * 32 + tid) * NP1 + j];
  __syncthreads();
  float s[4];
#pragma unroll
  for (int r = 0; r < 4; ++r) {
    int i = r * 256 + tid;
    float a = 0.f;
#pragma unroll
    for (int d = 0; d < 32; ++d) a += kp[((size_t)bg * 32 + d) * NP1 + i] * qj[d];
    s[r] = a;
  }
  float m = fmaxf(fmaxf(s[0], s[1]), fmaxf(s[2], s[3]));
  for (int o = 32; o > 0; o >>= 1) m = fmaxf(m, __shfl_xor(m, o, 64));
  if ((tid & 63) == 0) sred[tid >> 6] = m;
  __syncthreads();
  m = fmaxf(fmaxf(sred[0], sred[1]), fmaxf(sred[2], sred[3]));
  float e[4], ls = 0.f;
#pragma unroll
  for (int r = 0; r < 4; ++r) { e[r] = __expf(s[r] - m); ls += e[r]; }
  for (int o = 32; o > 0; o >>= 1) ls += __shfl_xor(ls, o, 64);
  if ((tid & 63) == 0) sred[4 + (tid >> 6)] = ls;
  __syncthreads();
  float inv = 1.f / (sred[4] + sred[5] + sred[6] + sred[7]);
#pragma unroll
  for (int r = 0; r < 4; ++r) {
    int i = r * 256 + tid;
    float am = e[r] * inv;
    Tt[((size_t)bg * NP1 + j) * NP1 + i] = 0.5f * (((i == j) ? 1.f : 0.f) - am);
  }
}

// ---------------------------------------------------------------------------
// K4: flash attention W1 = Vf @ softmax_i(Kf^T q)  -- split-K partials
// grid (jt 16, kc 4, bg 4); 64 queries/block; keys: kc-th quarter of 16384
// ---------------------------------------------------------------------------
__global__ __launch_bounds__(256) void k_flashW1(
    const float* __restrict__ qkv, const float* __restrict__ qp,
    float* __restrict__ pacc, float* __restrict__ pmb, float* __restrict__ plb) {
  int jt = blockIdx.x, kc = blockIdx.y, bg = blockIdx.z;
  int b = bg >> 1, g = bg & 1;
  int tid = threadIdx.x, j = tid & 63, quad = tid >> 6;
  __shared__ float Qs[32][64];
  __shared__ float Ks[32][64];
  __shared__ float Ss[64][64];
  __shared__ float Vs[64][64];
  __shared__ float red4[4][64];
  __shared__ float smM[64], smL[64], smScale[64];

  for (int l = tid; l < 32 * 64; l += 256) {
    int d = l >> 6, jj = l & 63;
    Qs[d][jj] = qp[((size_t)bg * 32 + d) * NP1 + jt * 64 + jj];
  }
  if (tid < 64) { smM[tid] = -1e30f; smL[tid] = 0.f; }
  float acc0[16], acc1[16];
#pragma unroll
  for (int r = 0; r < 16; ++r) { acc0[r] = 0.f; acc1[r] = 0.f; }
  const float* Kbase = qkv + ((size_t)b * 384 + 64 + g * 32) * HWN;
  const float* Vbase = qkv + ((size_t)b * 384 + 128 + g * 128) * HWN;
  int i0base = kc * 4096;
  __syncthreads();

  for (int chk = 0; chk < 64; ++chk) {
    int i0 = i0base + chk * 64;
    __syncthreads();  // protect Ks/Vs/Ss from previous iteration's readers
    for (int l = tid; l < 2048; l += 256) {
      int d = l >> 6, ii = l & 63;
      Ks[d][ii] = Kbase[(size_t)d * HWN + i0 + ii];
    }
    for (int l = tid; l < 4096; l += 256) {
      int c2 = l >> 6, ii = l & 63;
      Vs[c2][ii] = Vbase[(size_t)c2 * HWN + i0 + ii];
    }
    __syncthreads();
    // scores S[key 64][query 64]
    float sacc[4][4] = {};
#pragma unroll
    for (int d = 0; d < 32; ++d) {
      float kv[4], qv[4];
#pragma unroll
      for (int r = 0; r < 4; ++r) kv[r] = Ks[d][(tid >> 4) * 4 + r];
#pragma unroll
      for (int c = 0; c < 4; ++c) qv[c] = Qs[d][(tid & 15) * 4 + c];
#pragma unroll
      for (int r = 0; r < 4; ++r)
#pragma unroll
        for (int c = 0; c < 4; ++c) sacc[r][c] += kv[r] * qv[c];
    }
#pragma unroll
    for (int r = 0; r < 4; ++r)
#pragma unroll
      for (int c = 0; c < 4; ++c) Ss[(tid >> 4) * 4 + r][(tid & 15) * 4 + c] = sacc[r][c];
    __syncthreads();
    // online softmax over keys, per query column j (4 threads/column)
    float pmax = -1e30f;
#pragma unroll
    for (int r = 0; r < 16; ++r) pmax = fmaxf(pmax, Ss[quad * 16 + r][j]);
    red4[quad][j] = pmax;
    __syncthreads();
    if (quad == 0) {
      float mn = fmaxf(fmaxf(red4[0][j], red4[1][j]), fmaxf(red4[2][j], red4[3][j]));
      mn = fmaxf(mn, smM[j]);
      smScale[j] = __expf(smM[j] - mn);
      smM[j] = mn;
    }
    __syncthreads();
    float mn = smM[j];
    float ps = 0.f;
#pragma unroll
    for (int r = 0; r < 16; ++r) {
      float e = __expf(Ss[quad * 16 + r][j] - mn);
      Ss[quad * 16 + r][j] = e;
      ps += e;
    }
    red4[quad][j] = ps;
    __syncthreads();
    if (quad == 0)
      smL[j] = smL[j] * smScale[j] + red4[0][j] + red4[1][j] + red4[2][j] + red4[3][j];
    float sc = smScale[j];
#pragma unroll
    for (int r = 0; r < 16; ++r) { acc0[r] *= sc; acc1[r] *= sc; }
    // PV phase 0: V channels 0..63
    for (int ii = 0; ii < 64; ++ii) {
      float pv = Ss[ii][j];
#pragma unroll
      for (int r = 0; r < 16; ++r) acc0[r] += pv * Vs[quad * 16 + r][ii];
    }
    __syncthreads();
    for (int l = tid; l < 4096; l += 256) {
      int c2 = l >> 6, ii = l & 63;
      Vs[c2][ii] = Vbase[(size_t)(64 + c2) * HWN + i0 + ii];
    }
    __syncthreads();
    // PV phase 1: V channels 64..127
    for (int ii = 0; ii < 64; ++ii) {
      float pv = Ss[ii][j];
#pragma unroll
      for (int r = 0; r < 16; ++r) acc1[r] += pv * Vs[quad * 16 + r][ii];
    }
  }
  size_t pb = (((size_t)bg * 16 + jt) * 4 + kc) * 8192;  // 128*64 per partial
#pragma unroll
  for (int r = 0; r < 16; ++r) {
    pacc[pb + (size_t)(quad * 16 + r) * 64 + j] = acc0[r];
    pacc[pb + (size_t)(64 + quad * 16 + r) * 64 + j] = acc1[r];
  }
  if (tid < 64) {
    int pi = ((bg * 16 + jt) * 4 + kc) * 64 + j;
    pmb[pi] = smM[j];
    plb[pi] = smL[j];
  }
}

// ---------------------------------------------------------------------------
// K5: combine split-K partials -> W2acc (Neumann term 0) and R0
// ---------------------------------------------------------------------------
__global__ __launch_bounds__(256) void k_combine(
    const float* __restrict__ pacc, const float* __restrict__ pmb,
    const float* __restrict__ plb, float* __restrict__ W2, float* __restrict__ R0) {
  int jt = blockIdx.x, bg = blockIdx.y;
  int tid = threadIdx.x, j = tid & 63, quad = tid >> 6;
  __shared__ float wk[4][64];
  if (tid < 64) {
    float mv[4], lv[4], m = -1e30f;
#pragma unroll
    for (int kc = 0; kc < 4; ++kc) {
      int pi = ((bg * 16 + jt) * 4 + kc) * 64 + j;
      mv[kc] = pmb[pi]; lv[kc] = plb[pi];
      m = fmaxf(m, mv[kc]);
    }
    float l = 0.f, w[4];
#pragma unroll
    for (int kc = 0; kc < 4; ++kc) { w[kc] = __expf(mv[kc] - m); l += lv[kc] * w[kc]; }
    float inv = 1.f / l;
#pragma unroll
    for (int kc = 0; kc < 4; ++kc) wk[kc][j] = w[kc] * inv;
  }
  __syncthreads();
  for (int r = 0; r < 32; ++r) {
    int c2 = quad * 32 + r;
    float v = 0.f;
#pragma unroll
    for (int kc = 0; kc < 4; ++kc)
      v += pacc[((((size_t)bg * 16 + jt) * 4 + kc) * 128 + c2) * 64 + j] * wk[kc][j];
    size_t o = ((size_t)bg * 128 + c2) * NP1 + jt * 64 + j;
    W2[o] = v;
    R0[o] = v;
  }
}

// ---------------------------------------------------------------------------
// K6: Neumann step: Rn = R @ Tt^T (contract over i), W2 += Rn
// grid (jt 16, ct 4, bg 4); 32 rows x 64 cols per block
// ---------------------------------------------------------------------------
__global__ __launch_bounds__(256) void k_rt(
    const float* __restrict__ R, const float* __restrict__ Tt,
    float* __restrict__ Rn, float* __restrict__ W2) {
  int jt = blockIdx.x, ct = blockIdx.y, bg = blockIdx.z;
  int tid = threadIdx.x, j = tid & 63, cg = tid >> 6;
  __shared__ float Rs[32][33];
  __shared__ float Ts[64][33];
  float acc[8] = {};
  for (int i0 = 0; i0 < NP1; i0 += 32) {
    for (int l = tid; l < 32 * 32; l += 256) {
      int rr = l >> 5, kk = l & 31;
      Rs[rr][kk] = R[((size_t)bg * 128 + ct * 32 + rr) * NP1 + i0 + kk];
    }
    for (int l = tid; l < 64 * 32; l += 256) {
      int jj = l >> 5, kk = l & 31;
      Ts[jj][kk] = Tt[((size_t)bg * NP1 + jt * 64 + jj) * NP1 + i0 + kk];
    }
    __syncthreads();
#pragma unroll
    for (int kk = 0; kk < 32; ++kk) {
      float tv = Ts[j][kk];
#pragma unroll
      for (int r = 0; r < 8; ++r) acc[r] += Rs[cg * 8 + r][kk] * tv;
    }
    __syncthreads();
  }
#pragma unroll
  for (int r = 0; r < 8; ++r) {
    size_t o = ((size_t)bg * 128 + ct * 32 + cg * 8 + r) * NP1 + jt * 64 + j;
    Rn[o] = acc[r];
    W2[o] += acc[r];
  }
}

// ---------------------------------------------------------------------------
// K7: flash attention O = 0.5*( W2 @ softmax_i(k^T Qf) + W2[:, i1(j)] )
// grid (jt 256, bg 4); 64 queries/block; 1024 keys in 16 chunks
// ---------------------------------------------------------------------------
__global__ __launch_bounds__(256) void k_flashO(
    const float* __restrict__ qkv, const float* __restrict__ kp,
    const float* __restrict__ W2, float* __restrict__ O) {
  int jt = blockIdx.x, bg = blockIdx.y;
  int b = bg >> 1, g = bg & 1;
  int tid = threadIdx.x, j = tid & 63, quad = tid >> 6;
  __shared__ float Qs[32][64];
  __shared__ float Ks[32][64];
  __shared__ float Ss[64][64];
  __shared__ float Ws[64][64];
  __shared__ float red4[4][64];
  __shared__ float smM[64], smL[64], smScale[64];

  const float* Qbase = qkv + ((size_t)b * 384 + g * 32) * HWN;
  for (int l = tid; l < 32 * 64; l += 256) {
    int d = l >> 6, jj = l & 63;
    Qs[d][jj] = Qbase[(size_t)d * HWN + jt * 64 + jj];
  }
  if (tid < 64) { smM[tid] = -1e30f; smL[tid] = 0.f; }
  float acc0[16], acc1[16];
#pragma unroll
  for (int r = 0; r < 16; ++r) { acc0[r] = 0.f; acc1[r] = 0.f; }
  __syncthreads();

  for (int chk = 0; chk < 16; ++chk) {
    int i0 = chk * 64;
    __syncthreads();
    for (int l = tid; l < 2048; l += 256) {
      int d = l >> 6, ii = l & 63;
      Ks[d][ii] = kp[((size_t)bg * 32 + d) * NP1 + i0 + ii];
    }
    for (int l = tid; l < 4096; l += 256) {
      int c2 = l >> 6, ii = l & 63;
      Ws[c2][ii] = W2[((size_t)bg * 128 + c2) * NP1 + i0 + ii];
    }
    __syncthreads();
    float sacc[4][4] = {};
#pragma unroll
    for (int d = 0; d < 32; ++d) {
      float kv[4], qv[4];
#pragma unroll
      for (int r = 0; r < 4; ++r) kv[r] = Ks[d][(tid >> 4) * 4 + r];
#pragma unroll
      for (int c = 0; c < 4; ++c) qv[c] = Qs[d][(tid & 15) * 4 + c];
#pragma unroll
      for (int r = 0; r < 4; ++r)
#pragma unroll
        for (int c = 0; c < 4; ++c) sacc[r][c] += kv[r] * qv[c];
    }
#pragma unroll
    for (int r = 0; r < 4; ++r)
#pragma unroll
      for (int c = 0; c < 4; ++c) Ss[(tid >> 4) * 4 + r][(tid & 15) * 4 + c] = sacc[r][c];
    __syncthreads();
    float pmax = -1e30f;
#pragma unroll
    for (int r = 0; r < 16; ++r) pmax = fmaxf(pmax, Ss[quad * 16 + r][j]);
    red4[quad][j] = pmax;
    __syncthreads();
    if (quad == 0) {
      float mn = fmaxf(fmaxf(red4[0][j], red4[1][j]), fmaxf(red4[2][j], red4[3][j]));
      mn = fmaxf(mn, smM[j]);
      smScale[j] = __expf(smM[j] - mn);
      smM[j] = mn;
    }
    __syncthreads();
    float mn = smM[j];
    float ps = 0.f;
#pragma unroll
    for (int r = 0; r < 16; ++r) {
      float e = __expf(Ss[quad * 16 + r][j] - mn);
      Ss[quad * 16 + r][j] = e;
      ps += e;
    }
    red4[quad][j] = ps;
    __syncthreads();
    if (quad == 0)
      smL[j] = smL[j] * smScale[j] + red4[0][j] + red4[1][j] + red4[2][j] + red4[3][j];
    float sc = smScale[j];
#pragma unroll
    for (int r = 0; r < 16; ++r) { acc0[r] *= sc; acc1[r] *= sc; }
    for (int ii = 0; ii < 64; ++ii) {
      float pv = Ss[ii][j];
#pragma unroll
      for (int r = 0; r < 16; ++r) acc0[r] += pv * Ws[quad * 16 + r][ii];
    }
    __syncthreads();
    for (int l = tid; l < 4096; l += 256) {
      int c2 = l >> 6, ii = l & 63;
      Ws[c2][ii] = W2[((size_t)bg * 128 + 64 + c2) * NP1 + i0 + ii];
    }
    __syncthreads();
    for (int ii = 0; ii < 64; ++ii) {
      float pv = Ss[ii][j];
#pragma unroll
      for (int r = 0; r < 16; ++r) acc1[r] += pv * Ws[quad * 16 + r][ii];
    }
  }
  __syncthreads();  // make quad0's final smL visible to all
  float linv = 1.f / smL[j];
  int jg = jt * 64 + j;
  int hh = jg >> 7, ww = jg & 127;
  int i1 = (hh >> 2) * 32 + (ww >> 2);
#pragma unroll
  for (int r = 0; r < 16; ++r) {
    int c2a = quad * 16 + r;
    float v0 = acc0[r] * linv + W2[((size_t)bg * 128 + c2a) * NP1 + i1];
    O[((size_t)bg * 128 + c2a) * HWN + jg] = 0.5f * v0;
    int c2b = 64 + quad * 16 + r;
    float v1 = acc1[r] * linv + W2[((size_t)bg * 128 + c2b) * NP1 + i1];
    O[((size_t)bg * 128 + c2b) * HWN + jg] = 0.5f * v1;
  }
}

// ---------------------------------------------------------------------------
// K8: out = gamma * (out_w @ O + out_b) + x   (mode==0)
// O viewed as (2,256,16384) is exactly the (bg,c2) layout flattened.
// ---------------------------------------------------------------------------
__global__ __launch_bounds__(256) void k_out(
    const float* __restrict__ O, const float* __restrict__ w,
    const float* __restrict__ bias, const float* __restrict__ x,
    const float* __restrict__ gamma, const int* __restrict__ mode,
    float* __restrict__ out) {
  int pt = blockIdx.x * 64, ot = blockIdx.y * 64, bb = blockIdx.z;
  int tid = threadIdx.x;
  __shared__ float Wsm[64][33];
  __shared__ float Xsm[32][65];
  float acc[4][4] = {};
  const float* Ob = O + (size_t)bb * 256 * HWN;
  for (int c0 = 0; c0 < 256; c0 += 32) {
    for (int l = tid; l < 64 * 32; l += 256) {
      int oo = l >> 5, cc = l & 31;
      Wsm[oo][cc] = w[(size_t)(ot + oo) * 256 + c0 + cc];
    }
    for (int l = tid; l < 32 * 64; l += 256) {
      int cc = l >> 6, pp = l & 63;
      Xsm[cc][pp] = Ob[(size_t)(c0 + cc) * HWN + pt + pp];
    }
    __syncthreads();
#pragma unroll
    for (int kk = 0; kk < 32; ++kk) {
      float wv[4], xv[4];
#pragma unroll
      for (int r = 0; r < 4; ++r) wv[r] = Wsm[(tid >> 4) * 4 + r][kk];
#pragma unroll
      for (int s = 0; s < 4; ++s) xv[s] = Xsm[kk][(tid & 15) * 4 + s];
#pragma unroll
      for (int r = 0; r < 4; ++r)
#pragma unroll
        for (int s = 0; s < 4; ++s) acc[r][s] += wv[r] * xv[s];
    }
    __syncthreads();
  }
  float gm = gamma[0];
  int md = mode[0];
#pragma unroll
  for (int r = 0; r < 4; ++r) {
    int oc = ot + (tid >> 4) * 4 + r;
    float bv = bias[oc];
#pragma unroll
    for (int s = 0; s < 4; ++s) {
      int pp = pt + (tid & 15) * 4 + s;
      size_t o = ((size_t)bb * 256 + oc) * HWN + pp;
      float t = acc[r][s] + bv;
      out[o] = (md == 0) ? (gm * t + x[o]) : t;
    }
  }
}

// ---------------------------------------------------------------------------
extern "C" void kernel_launch(void* const* d_in, const int* in_sizes, int n_in,
                              void* d_out, int out_size, void* d_ws, size_t ws_size,
                              hipStream_t stream) {
  (void)in_sizes; (void)n_in; (void)out_size;
  const float* x      = (const float*)d_in[0];
  const float* qkv_w  = (const float*)d_in[1];
  const float* qkv_b  = (const float*)d_in[2];
  const float* out_w  = (const float*)d_in[3];
  const float* out_b  = (const float*)d_in[4];
  const float* gamma  = (const float*)d_in[5];
  const int*   mode   = (const int*)d_in[6];
  float* out = (float*)d_out;
  float* ws  = (float*)d_ws;

  // workspace layout (floats)
  const size_t OFF_QKV = 0;                        // 2*384*16384 = 12,582,912
  const size_t OFF_QP  = OFF_QKV + 12582912;       // 131,072
  const size_t OFF_KP  = OFF_QP  + 131072;         // 131,072
  const size_t OFF_T   = OFF_KP  + 131072;         // 4*1024*1024 = 4,194,304
  const size_t OFF_W2  = OFF_T   + 4194304;        // 524,288
  const size_t OFF_RA  = OFF_W2  + 524288;         // 524,288
  const size_t OFF_RB  = OFF_RA  + 524288;         // 524,288
  const size_t OFF_PM  = OFF_RB  + 524288;         // 16,384
  const size_t OFF_PL  = OFF_PM  + 16384;          // 16,384
  const size_t OFF_O   = OFF_PL  + 16384;          // 4*128*16384 = 8,388,608
  const size_t OFF_PACC= OFF_O;                    // alias: dead before O written
  const size_t NEED = (OFF_O + 8388608) * sizeof(float);  // ~108.1 MB
  if (ws_size < NEED) return;  // visible failure instead of OOB writes

  float* qkv  = ws + OFF_QKV;
  float* qp   = ws + OFF_QP;
  float* kp   = ws + OFF_KP;
  float* Tt   = ws + OFF_T;
  float* W2   = ws + OFF_W2;
  float* Ra   = ws + OFF_RA;
  float* Rb   = ws + OFF_RB;
  float* pmb  = ws + OFF_PM;
  float* plb  = ws + OFF_PL;
  float* Obuf = ws + OFF_O;
  float* pacc = ws + OFF_PACC;

  k_qkv<<<dim3(256, 6, 2), 256, 0, stream>>>(x, qkv_w, qkv_b, qkv);
  k_pool<<<512, 256, 0, stream>>>(qkv, qp, kp);
  k_amT<<<dim3(1024, 4), 256, 0, stream>>>(qp, kp, Tt);
  k_flashW1<<<dim3(16, 4, 4), 256, 0, stream>>>(qkv, qp, pacc, pmb, plb);
  k_combine<<<dim3(16, 4), 256, 0, stream>>>(pacc, pmb, plb, W2, Ra);
  float* rin = Ra;
  float* rout = Rb;
  for (int it = 0; it < 16; ++it) {
    k_rt<<<dim3(16, 4, 4), 256, 0, stream>>>(rin, Tt, rout, W2);
    float* t = rin; rin = rout; rout = t;
  }
  k_flashO<<<dim3(256, 4), 256, 0, stream>>>(qkv, kp, W2, Obuf);
  k_out<<<dim3(256, 4, 2), 256, 0, stream>>>(Obuf, out_w, out_b, x, gamma, mode, out);
}

// Round 2
// 631.407 us; speedup vs baseline: 5.6813x; 5.6813x over previous
//
#include <hip/hip_runtime.h>
#include <cstdint>
#include <cstddef>

#define HWN 16384   // H*W
#define NP1 1024    // pooled positions

typedef __attribute__((ext_vector_type(8))) short bf16x8;            // MFMA A/B frag
typedef __attribute__((ext_vector_type(8))) unsigned short ushort8v;
typedef __attribute__((ext_vector_type(4))) unsigned short ushort4v;
typedef __attribute__((ext_vector_type(2))) unsigned int uint2v;
typedef __attribute__((ext_vector_type(4))) float f32x4;

__device__ __forceinline__ unsigned short f2bu(float f) {
  unsigned int u = __builtin_bit_cast(unsigned int, f);
  u = (u + 0x7FFFu + ((u >> 16) & 1u)) >> 16;   // RNE
  return (unsigned short)u;
}
__device__ __forceinline__ float b2f(unsigned short s) {
  unsigned int u = ((unsigned int)s) << 16;
  return __builtin_bit_cast(float, u);
}
#define MFMA16(A,B,C) __builtin_amdgcn_mfma_f32_16x16x32_bf16((A),(B),(C),0,0,0)

// ---------------------------------------------------------------------------
// K0: cast+transpose x -> xbT[b][p][c] bf16 ; cast weights -> wqb, wob bf16
// ---------------------------------------------------------------------------
__global__ __launch_bounds__(256) void k_cast(
    const float* __restrict__ x, const float* __restrict__ qkv_w,
    const float* __restrict__ out_w, unsigned short* __restrict__ xbT,
    unsigned short* __restrict__ wqb, unsigned short* __restrict__ wob) {
  int bid = blockIdx.x, t = threadIdx.x;
  if (bid < 2048) {
    __shared__ float Lt[64][65];
    int b = bid >> 10, rest = bid & 1023, ct = rest >> 8, pt = rest & 255;
    const float* xp = x + ((size_t)b * 256 + ct * 64) * HWN + pt * 64;
    for (int it = 0; it < 16; ++it) {
      int idx = it * 256 + t; int cc = idx >> 6, pp = idx & 63;
      Lt[cc][pp] = xp[(size_t)cc * HWN + pp];
    }
    __syncthreads();
    int prow = t >> 2, c0 = (t & 3) * 16;
    unsigned short* dst = xbT + ((size_t)b * HWN + pt * 64 + prow) * 256 + ct * 64 + c0;
    ushort8v o1, o2;
#pragma unroll
    for (int q = 0; q < 8; ++q) o1[q] = f2bu(Lt[c0 + q][prow]);
#pragma unroll
    for (int q = 0; q < 8; ++q) o2[q] = f2bu(Lt[c0 + 8 + q][prow]);
    *(ushort8v*)dst = o1;
    *(ushort8v*)(dst + 8) = o2;
  } else {
    int base = (bid - 2048) * 1024 + t * 4;     // 160 blocks cover 163840 elems
    if (base < 98304) {
      float4 v = *(const float4*)(qkv_w + base);
      ushort4v o; o[0]=f2bu(v.x); o[1]=f2bu(v.y); o[2]=f2bu(v.z); o[3]=f2bu(v.w);
      *(ushort4v*)(wqb + base) = o;
    } else {
      int b2 = base - 98304;
      float4 v = *(const float4*)(out_w + b2);
      ushort4v o; o[0]=f2bu(v.x); o[1]=f2bu(v.y); o[2]=f2bu(v.z); o[3]=f2bu(v.w);
      *(ushort4v*)(wob + b2) = o;
    }
  }
}

// ---------------------------------------------------------------------------
// K1: qkv[b][o][p] = sum_c wqb[o][c] * xbT[p][c] + bias  (MFMA), store bf16
// ---------------------------------------------------------------------------
__global__ __launch_bounds__(256) void k_qkv(
    const unsigned short* __restrict__ wqb, const unsigned short* __restrict__ xbT,
    const float* __restrict__ qkv_b, unsigned short* __restrict__ qkvb) {
  int pt = blockIdx.x, ot = blockIdx.y, b = blockIdx.z;
  int tid = threadIdx.x, w = tid >> 6, lane = tid & 63;
  int lg = lane >> 4, ln = lane & 15;
  f32x4 acc[4] = {};
  const int orow = ot * 64 + w * 16 + ln;
#pragma unroll
  for (int ks = 0; ks < 8; ++ks) {
    int c0 = ks * 32;
    bf16x8 aw = *(const bf16x8*)(wqb + (size_t)orow * 256 + c0 + lg * 8);
#pragma unroll
    for (int nt = 0; nt < 4; ++nt) {
      bf16x8 bx = *(const bf16x8*)(xbT + ((size_t)b * HWN + pt * 64 + nt * 16 + ln) * 256 + c0 + lg * 8);
      acc[nt] = MFMA16(aw, bx, acc[nt]);
    }
  }
#pragma unroll
  for (int nt = 0; nt < 4; ++nt)
#pragma unroll
    for (int r = 0; r < 4; ++r) {
      int o = ot * 64 + w * 16 + lg * 4 + r;
      int p = pt * 64 + nt * 16 + ln;
      qkvb[((size_t)b * 384 + o) * HWN + p] = f2bu(acc[nt][r] + qkv_b[o]);
    }
}

// ---------------------------------------------------------------------------
// K2: 4x4 avg pool -> qpb[bg][32 d][1024 i] bf16, kpt[bg][1024 i][32 d] bf16
// ---------------------------------------------------------------------------
__global__ __launch_bounds__(256) void k_pool(
    const unsigned short* __restrict__ qkvb, unsigned short* __restrict__ qpb,
    unsigned short* __restrict__ kpt) {
  int idx = blockIdx.x * 256 + threadIdx.x;   // 131072
  int i1 = idx & 1023, cc = (idx >> 10) & 31, bg = idx >> 15;
  int b = bg >> 1, g = bg & 1;
  int h1 = i1 >> 5, w1 = i1 & 31;
  const unsigned short* bq = qkvb + (size_t)(b * 384 + g * 32 + cc) * HWN;
  const unsigned short* bk = qkvb + (size_t)(b * 384 + 64 + g * 32 + cc) * HWN;
  float sq = 0.f, sk = 0.f;
#pragma unroll
  for (int sh = 0; sh < 4; ++sh) {
    int off = (h1 * 4 + sh) * 128 + w1 * 4;
    ushort4v vq = *(const ushort4v*)(bq + off);
    ushort4v vk = *(const ushort4v*)(bk + off);
#pragma unroll
    for (int e = 0; e < 4; ++e) { sq += b2f(vq[e]); sk += b2f(vk[e]); }
  }
  qpb[((size_t)bg * 32 + cc) * NP1 + i1] = f2bu(sq * 0.0625f);
  kpt[((size_t)bg * NP1 + i1) * 32 + cc] = f2bu(sk * 0.0625f);
}

// ---------------------------------------------------------------------------
// K3: A_m (max-free col softmax over i) -> Tt[bg][j][i] = 0.5*(d(i,j)-A_m) bf16
// Two-pass MFMA: pass1 accumulates l[j], pass2 recomputes scores and writes Tt.
// ---------------------------------------------------------------------------
__global__ __launch_bounds__(256) void k_amT(
    const unsigned short* __restrict__ qpb, const unsigned short* __restrict__ kpt,
    unsigned short* __restrict__ Tt) {
  int jt = blockIdx.x, bg = blockIdx.y;
  int tid = threadIdx.x, w = tid >> 6, lane = tid & 63;
  int lg = lane >> 4, ln = lane & 15;
  __shared__ float redL[4][64];
  __shared__ float smL[64];
  bf16x8 bq[4];
#pragma unroll
  for (int nt = 0; nt < 4; ++nt) {
    ushort8v t8;
#pragma unroll
    for (int jr = 0; jr < 8; ++jr)
      t8[jr] = qpb[((size_t)bg * 32 + lg * 8 + jr) * NP1 + jt * 64 + nt * 16 + ln];
    bq[nt] = __builtin_bit_cast(bf16x8, t8);
  }
  float lsum[4] = {0.f, 0.f, 0.f, 0.f};
  for (int chk = 0; chk < 16; ++chk) {
    int i0 = chk * 64;
    bf16x8 ak = *(const bf16x8*)(kpt + ((size_t)bg * NP1 + i0 + w * 16 + ln) * 32 + lg * 8);
#pragma unroll
    for (int nt = 0; nt < 4; ++nt) {
      f32x4 z = {0.f, 0.f, 0.f, 0.f};
      f32x4 s = MFMA16(ak, bq[nt], z);
#pragma unroll
      for (int r = 0; r < 4; ++r) lsum[nt] += __expf(s[r]);
    }
  }
#pragma unroll
  for (int nt = 0; nt < 4; ++nt) {
    float v = lsum[nt];
    v += __shfl_xor(v, 16); v += __shfl_xor(v, 32);
    if (lane < 16) redL[w][nt * 16 + lane] = v;
  }
  __syncthreads();
  if (tid < 64) smL[tid] = redL[0][tid] + redL[1][tid] + redL[2][tid] + redL[3][tid];
  __syncthreads();
  float linv[4];
#pragma unroll
  for (int nt = 0; nt < 4; ++nt) linv[nt] = 1.f / smL[nt * 16 + ln];
  for (int chk = 0; chk < 16; ++chk) {
    int i0 = chk * 64;
    bf16x8 ak = *(const bf16x8*)(kpt + ((size_t)bg * NP1 + i0 + w * 16 + ln) * 32 + lg * 8);
#pragma unroll
    for (int nt = 0; nt < 4; ++nt) {
      f32x4 z = {0.f, 0.f, 0.f, 0.f};
      f32x4 s = MFMA16(ak, bq[nt], z);
      int j = jt * 64 + nt * 16 + ln;
      int ib = i0 + w * 16 + lg * 4;
      unsigned short e0 = f2bu(0.5f * (((ib + 0) == j ? 1.f : 0.f) - __expf(s[0]) * linv[nt]));
      unsigned short e1 = f2bu(0.5f * (((ib + 1) == j ? 1.f : 0.f) - __expf(s[1]) * linv[nt]));
      unsigned short e2 = f2bu(0.5f * (((ib + 2) == j ? 1.f : 0.f) - __expf(s[2]) * linv[nt]));
      unsigned short e3 = f2bu(0.5f * (((ib + 3) == j ? 1.f : 0.f) - __expf(s[3]) * linv[nt]));
      uint2v pk;
      pk[0] = (unsigned)e0 | ((unsigned)e1 << 16);
      pk[1] = (unsigned)e2 | ((unsigned)e3 << 16);
      *(uint2v*)(Tt + ((size_t)bg * NP1 + j) * NP1 + ib) = pk;
    }
  }
}

// ---------------------------------------------------------------------------
// K4: flash W1 = Vf @ exp(Kf^T q) (max-free), split-K partials (MFMA)
// grid (jt 16, kc 8, bg 4); per block: 128 c x 64 j, keys kc*2048..+2048
// ---------------------------------------------------------------------------
__global__ __launch_bounds__(256) void k_flashW1(
    const unsigned short* __restrict__ qkvb, const unsigned short* __restrict__ qpb,
    float* __restrict__ pacc, float* __restrict__ pl) {
  int jt = blockIdx.x, kc = blockIdx.y, bg = blockIdx.z;
  int b = bg >> 1, g = bg & 1;
  int tid = threadIdx.x, w = tid >> 6, lane = tid & 63;
  int lg = lane >> 4, ln = lane & 15;
  __shared__ unsigned short PtS[64][72];
  __shared__ float redL[4][64];
  const int Kch = b * 384 + 64 + g * 32;
  const int Vch = b * 384 + 128 + g * 128;
  bf16x8 bq[4];
#pragma unroll
  for (int nt = 0; nt < 4; ++nt) {
    ushort8v t8;
#pragma unroll
    for (int jr = 0; jr < 8; ++jr)
      t8[jr] = qpb[((size_t)bg * 32 + lg * 8 + jr) * NP1 + jt * 64 + nt * 16 + ln];
    bq[nt] = __builtin_bit_cast(bf16x8, t8);
  }
  f32x4 acc[2][4] = {};
  float lsum[4] = {0.f, 0.f, 0.f, 0.f};
  for (int chk = 0; chk < 32; ++chk) {
    int i0 = kc * 2048 + chk * 64;
    ushort8v ta;
#pragma unroll
    for (int jr = 0; jr < 8; ++jr)
      ta[jr] = qkvb[(size_t)(Kch + lg * 8 + jr) * HWN + i0 + w * 16 + ln];
    bf16x8 ak = __builtin_bit_cast(bf16x8, ta);
    float e[4][4];
#pragma unroll
    for (int nt = 0; nt < 4; ++nt) {
      f32x4 z = {0.f, 0.f, 0.f, 0.f};
      f32x4 s = MFMA16(ak, bq[nt], z);
#pragma unroll
      for (int r = 0; r < 4; ++r) { e[nt][r] = __expf(s[r]); lsum[nt] += e[nt][r]; }
    }
    __syncthreads();   // previous PV readers of PtS done
#pragma unroll
    for (int nt = 0; nt < 4; ++nt) {
      uint2v pk;
      pk[0] = (unsigned)f2bu(e[nt][0]) | ((unsigned)f2bu(e[nt][1]) << 16);
      pk[1] = (unsigned)f2bu(e[nt][2]) | ((unsigned)f2bu(e[nt][3]) << 16);
      *(uint2v*)&PtS[nt * 16 + ln][w * 16 + lg * 4] = pk;
    }
    __syncthreads();   // P visible
#pragma unroll
    for (int ist = 0; ist < 2; ++ist) {
      bf16x8 bp[4];
#pragma unroll
      for (int nt = 0; nt < 4; ++nt)
        bp[nt] = *(const bf16x8*)&PtS[nt * 16 + ln][ist * 32 + lg * 8];
#pragma unroll
      for (int ct = 0; ct < 2; ++ct) {
        bf16x8 av = *(const bf16x8*)(qkvb + (size_t)(Vch + w * 32 + ct * 16 + ln) * HWN + i0 + ist * 32 + lg * 8);
#pragma unroll
        for (int nt = 0; nt < 4; ++nt)
          acc[ct][nt] = MFMA16(av, bp[nt], acc[ct][nt]);
      }
    }
  }
  size_t pb = (((size_t)bg * 16 + jt) * 8 + kc) * 8192;
#pragma unroll
  for (int ct = 0; ct < 2; ++ct)
#pragma unroll
    for (int nt = 0; nt < 4; ++nt)
#pragma unroll
      for (int r = 0; r < 4; ++r)
        pacc[pb + (size_t)(w * 32 + ct * 16 + lg * 4 + r) * 64 + nt * 16 + ln] = acc[ct][nt][r];
#pragma unroll
  for (int nt = 0; nt < 4; ++nt) {
    float v = lsum[nt];
    v += __shfl_xor(v, 16); v += __shfl_xor(v, 32);
    if (lane < 16) redL[w][nt * 16 + lane] = v;
  }
  __syncthreads();
  if (tid < 64)
    pl[(((size_t)bg * 16 + jt) * 8 + kc) * 64 + tid] =
        redL[0][tid] + redL[1][tid] + redL[2][tid] + redL[3][tid];
}

// ---------------------------------------------------------------------------
// K5: combine split-K partials -> W2 f32 (Neumann term 0) and R0 bf16
// ---------------------------------------------------------------------------
__global__ __launch_bounds__(256) void k_combine(
    const float* __restrict__ pacc, const float* __restrict__ pl,
    float* __restrict__ W2, unsigned short* __restrict__ R0) {
  int gid = blockIdx.x * 256 + threadIdx.x;   // 524288
  int bg = gid >> 17, rem = gid & 131071;
  int c = rem >> 10, j = rem & 1023;
  int jt = j >> 6, jj = j & 63;
  float s = 0.f, l = 0.f;
#pragma unroll
  for (int kc = 0; kc < 8; ++kc) {
    size_t pb = ((size_t)bg * 16 + jt) * 8 + kc;
    s += pacc[pb * 8192 + c * 64 + jj];
    l += pl[pb * 64 + jj];
  }
  float w1 = s / l;
  W2[gid] = w1;
  R0[gid] = f2bu(w1);
}

// ---------------------------------------------------------------------------
// K6: Neumann step (MFMA): Rn = R @ T, W2 += Rn ; last: W2b = bf16(W2+Rn)
// ---------------------------------------------------------------------------
__global__ __launch_bounds__(256) void k_rt(
    const unsigned short* __restrict__ Rin, const unsigned short* __restrict__ Tt,
    unsigned short* __restrict__ Rout, float* __restrict__ W2,
    unsigned short* __restrict__ W2b, int last) {
  int jt = blockIdx.x, bg = blockIdx.y;
  int tid = threadIdx.x, w = tid >> 6, lane = tid & 63;
  int lg = lane >> 4, ln = lane & 15;
  f32x4 acc[2][4] = {};
  for (int ks = 0; ks < 32; ++ks) {
    int i0 = ks * 32;
    bf16x8 bt[4];
#pragma unroll
    for (int nt = 0; nt < 4; ++nt)
      bt[nt] = *(const bf16x8*)(Tt + ((size_t)bg * NP1 + jt * 64 + nt * 16 + ln) * NP1 + i0 + lg * 8);
#pragma unroll
    for (int ct = 0; ct < 2; ++ct) {
      bf16x8 a = *(const bf16x8*)(Rin + ((size_t)bg * 128 + w * 32 + ct * 16 + ln) * NP1 + i0 + lg * 8);
#pragma unroll
      for (int nt = 0; nt < 4; ++nt)
        acc[ct][nt] = MFMA16(a, bt[nt], acc[ct][nt]);
    }
  }
#pragma unroll
  for (int ct = 0; ct < 2; ++ct)
#pragma unroll
    for (int nt = 0; nt < 4; ++nt)
#pragma unroll
      for (int r = 0; r < 4; ++r) {
        int c = w * 32 + ct * 16 + lg * 4 + r;
        int j = jt * 64 + nt * 16 + ln;
        size_t o = ((size_t)bg * 128 + c) * NP1 + j;
        float v = acc[ct][nt][r];
        if (last) W2b[o] = f2bu(W2[o] + v);
        else { Rout[o] = f2bu(v); W2[o] += v; }
      }
}

// ---------------------------------------------------------------------------
// K7: flash O = 0.5*( W2 @ exp(k^T Qf)/l + W2[:,i1(j)] )  (MFMA, max-free)
// grid (jt 256, bg 4); writes Ot[b][p][c] bf16 (transposed for k_out)
// ---------------------------------------------------------------------------
__global__ __launch_bounds__(256) void k_flashO(
    const unsigned short* __restrict__ qkvb, const unsigned short* __restrict__ kpt,
    const unsigned short* __restrict__ W2b, unsigned short* __restrict__ Ot) {
  int jt = blockIdx.x, bg = blockIdx.y;
  int b = bg >> 1, g = bg & 1;
  int tid = threadIdx.x, w = tid >> 6, lane = tid & 63;
  int lg = lane >> 4, ln = lane & 15;
  __shared__ unsigned short PtS[64][72];
  __shared__ float redL[4][64];
  __shared__ float smL[64];
  const int Qch = b * 384 + g * 32;
  bf16x8 bq[4];
#pragma unroll
  for (int nt = 0; nt < 4; ++nt) {
    ushort8v t8;
#pragma unroll
    for (int jr = 0; jr < 8; ++jr)
      t8[jr] = qkvb[(size_t)(Qch + lg * 8 + jr) * HWN + jt * 64 + nt * 16 + ln];
    bq[nt] = __builtin_bit_cast(bf16x8, t8);
  }
  f32x4 acc[2][4] = {};
  float lsum[4] = {0.f, 0.f, 0.f, 0.f};
  for (int chk = 0; chk < 16; ++chk) {
    int i0 = chk * 64;
    bf16x8 ak = *(const bf16x8*)(kpt + ((size_t)bg * NP1 + i0 + w * 16 + ln) * 32 + lg * 8);
    float e[4][4];
#pragma unroll
    for (int nt = 0; nt < 4; ++nt) {
      f32x4 z = {0.f, 0.f, 0.f, 0.f};
      f32x4 s = MFMA16(ak, bq[nt], z);
#pragma unroll
      for (int r = 0; r < 4; ++r) { e[nt][r] = __expf(s[r]); lsum[nt] += e[nt][r]; }
    }
    __syncthreads();
#pragma unroll
    for (int nt = 0; nt < 4; ++nt) {
      uint2v pk;
      pk[0] = (unsigned)f2bu(e[nt][0]) | ((unsigned)f2bu(e[nt][1]) << 16);
      pk[1] = (unsigned)f2bu(e[nt][2]) | ((unsigned)f2bu(e[nt][3]) << 16);
      *(uint2v*)&PtS[nt * 16 + ln][w * 16 + lg * 4] = pk;
    }
    __syncthreads();
#pragma unroll
    for (int ist = 0; ist < 2; ++ist) {
      bf16x8 bp[4];
#pragma unroll
      for (int nt = 0; nt < 4; ++nt)
        bp[nt] = *(const bf16x8*)&PtS[nt * 16 + ln][ist * 32 + lg * 8];
#pragma unroll
      for (int ct = 0; ct < 2; ++ct) {
        bf16x8 av = *(const bf16x8*)(W2b + ((size_t)bg * 128 + w * 32 + ct * 16 + ln) * NP1 + i0 + ist * 32 + lg * 8);
#pragma unroll
        for (int nt = 0; nt < 4; ++nt)
          acc[ct][nt] = MFMA16(av, bp[nt], acc[ct][nt]);
      }
    }
  }
#pragma unroll
  for (int nt = 0; nt < 4; ++nt) {
    float v = lsum[nt];
    v += __shfl_xor(v, 16); v += __shfl_xor(v, 32);
    if (lane < 16) redL[w][nt * 16 + lane] = v;
  }
  __syncthreads();
  if (tid < 64) smL[tid] = redL[0][tid] + redL[1][tid] + redL[2][tid] + redL[3][tid];
  __syncthreads();
#pragma unroll
  for (int nt = 0; nt < 4; ++nt) {
    int jj = nt * 16 + ln;
    int jg = jt * 64 + jj;
    float linv = 1.f / smL[jj];
    int i1 = (jg >> 9) * 32 + ((jg & 127) >> 2);
#pragma unroll
    for (int ct = 0; ct < 2; ++ct) {
      ushort4v o4;
#pragma unroll
      for (int r = 0; r < 4; ++r) {
        int c = w * 32 + ct * 16 + lg * 4 + r;
        float v = acc[ct][nt][r] * linv + b2f(W2b[((size_t)bg * 128 + c) * NP1 + i1]);
        o4[r] = f2bu(0.5f * v);
      }
      *(ushort4v*)(Ot + ((size_t)b * HWN + jg) * 256 + g * 128 + w * 32 + ct * 16 + lg * 4) = o4;
    }
  }
}

// ---------------------------------------------------------------------------
// K8: out = gamma * (wob @ Ot + out_b) + x  (MFMA, f32 epilogue)
// ---------------------------------------------------------------------------
__global__ __launch_bounds__(256) void k_out(
    const unsigned short* __restrict__ wob, const unsigned short* __restrict__ Ot,
    const float* __restrict__ out_b, const float* __restrict__ x,
    const float* __restrict__ gamma, const int* __restrict__ mode,
    float* __restrict__ out) {
  int pt = blockIdx.x, ot = blockIdx.y, b = blockIdx.z;
  int tid = threadIdx.x, w = tid >> 6, lane = tid & 63;
  int lg = lane >> 4, ln = lane & 15;
  f32x4 acc[4] = {};
  const int orow = ot * 64 + w * 16 + ln;
#pragma unroll
  for (int ks = 0; ks < 8; ++ks) {
    int c0 = ks * 32;
    bf16x8 aw = *(const bf16x8*)(wob + (size_t)orow * 256 + c0 + lg * 8);
#pragma unroll
    for (int nt = 0; nt < 4; ++nt) {
      bf16x8 bx = *(const bf16x8*)(Ot + ((size_t)b * HWN + pt * 64 + nt * 16 + ln) * 256 + c0 + lg * 8);
      acc[nt] = MFMA16(aw, bx, acc[nt]);
    }
  }
  float gm = gamma[0];
  int md = mode[0];
#pragma unroll
  for (int nt = 0; nt < 4; ++nt)
#pragma unroll
    for (int r = 0; r < 4; ++r) {
      int o = ot * 64 + w * 16 + lg * 4 + r;
      int p = pt * 64 + nt * 16 + ln;
      size_t off = ((size_t)b * 256 + o) * HWN + p;
      float v = acc[nt][r] + out_b[o];
      out[off] = (md == 0) ? (gm * v + x[off]) : v;
    }
}

// ---------------------------------------------------------------------------
extern "C" void kernel_launch(void* const* d_in, const int* in_sizes, int n_in,
                              void* d_out, int out_size, void* d_ws, size_t ws_size,
                              hipStream_t stream) {
  (void)in_sizes; (void)n_in; (void)out_size;
  const float* x     = (const float*)d_in[0];
  const float* qkv_w = (const float*)d_in[1];
  const float* qkv_b = (const float*)d_in[2];
  const float* out_w = (const float*)d_in[3];
  const float* out_b = (const float*)d_in[4];
  const float* gamma = (const float*)d_in[5];
  const int*   mode  = (const int*)d_in[6];
  float* out = (float*)d_out;

  char* wsb = (char*)d_ws;
  size_t off = 0;
  auto alloc = [&](size_t bytes) { char* p = wsb + off; off += bytes; return p; };
  unsigned short* xbT  = (unsigned short*)alloc(16777216);  // [2][16384][256]
  unsigned short* wqb  = (unsigned short*)alloc(196608);    // [384][256]
  unsigned short* wob  = (unsigned short*)alloc(131072);    // [256][256]
  unsigned short* qkvb = (unsigned short*)alloc(25165824);  // [2][384][16384]
  unsigned short* qpb  = (unsigned short*)alloc(262144);    // [4][32][1024]
  unsigned short* kpt  = (unsigned short*)alloc(262144);    // [4][1024][32]
  unsigned short* Tt   = (unsigned short*)alloc(8388608);   // [4][1024][1024]
  float*          pacc = (float*)alloc(16777216);           // [4][16][8][128][64]
  float*          pl   = (float*)alloc(131072);             // [4][16][8][64]
  float*          W2   = (float*)alloc(2097152);            // [4][128][1024]
  unsigned short* W2b  = (unsigned short*)alloc(1048576);
  unsigned short* Ra   = (unsigned short*)alloc(1048576);
  unsigned short* Rb   = (unsigned short*)alloc(1048576);
  unsigned short* Ot   = (unsigned short*)alloc(16777216);  // [2][16384][256]
  if (ws_size < off) return;   // ~90.1 MB

  k_cast<<<2208, 256, 0, stream>>>(x, qkv_w, out_w, xbT, wqb, wob);
  k_qkv<<<dim3(256, 6, 2), 256, 0, stream>>>(wqb, xbT, qkv_b, qkvb);
  k_pool<<<512, 256, 0, stream>>>(qkvb, qpb, kpt);
  k_amT<<<dim3(16, 4), 256, 0, stream>>>(qpb, kpt, Tt);
  k_flashW1<<<dim3(16, 8, 4), 256, 0, stream>>>(qkvb, qpb, pacc, pl);
  k_combine<<<2048, 256, 0, stream>>>(pacc, pl, W2, Ra);
  unsigned short* rin = Ra;
  unsigned short* rout = Rb;
  for (int it = 0; it < 12; ++it) {
    k_rt<<<dim3(16, 4), 256, 0, stream>>>(rin, Tt, rout, W2, W2b, it == 11 ? 1 : 0);
    unsigned short* t = rin; rin = rout; rout = t;
  }
  k_flashO<<<dim3(256, 4), 256, 0, stream>>>(qkvb, kpt, W2b, Ot);
  k_out<<<dim3(256, 4, 2), 256, 0, stream>>>(wob, Ot, out_b, x, gamma, mode, out);
}

// Round 3
// 444.936 us; speedup vs baseline: 8.0623x; 1.4191x over previous
//
#include <hip/hip_runtime.h>
#include <cstdint>
#include <cstddef>

#define HWN 16384   // H*W
#define NP1 1024    // pooled positions
#define RL2E 1.44269504f

typedef __attribute__((ext_vector_type(8))) short bf16x8;            // MFMA A/B frag
typedef __attribute__((ext_vector_type(8))) unsigned short ushort8v;
typedef __attribute__((ext_vector_type(4))) unsigned short ushort4v;
typedef __attribute__((ext_vector_type(2))) unsigned int uint2v;
typedef __attribute__((ext_vector_type(4))) float f32x4;

__device__ __forceinline__ unsigned short f2bu(float f) {
  unsigned int u = __builtin_bit_cast(unsigned int, f);
  u = (u + 0x7FFFu + ((u >> 16) & 1u)) >> 16;   // RNE
  return (unsigned short)u;
}
__device__ __forceinline__ float b2f(unsigned short s) {
  unsigned int u = ((unsigned int)s) << 16;
  return __builtin_bit_cast(float, u);
}
__device__ __forceinline__ bf16x8 scale_l2e(ushort8v t) {   // q-frag prescale by log2(e)
  ushort8v o;
#pragma unroll
  for (int q = 0; q < 8; ++q) o[q] = f2bu(RL2E * b2f(t[q]));
  return __builtin_bit_cast(bf16x8, o);
}
#define MFMA16(A,B,C) __builtin_amdgcn_mfma_f32_16x16x32_bf16((A),(B),(C),0,0,0)
// XOR-swizzled index (ushort units) for the 64x64 bf16 P tile: byte ^= (row&7)<<4
#define PIDX(r,c) ((((r) << 6) + (c)) ^ (((r) & 7) << 3))

// ---------------------------------------------------------------------------
// K0: cast+transpose x -> xbT[b][p][c] bf16 ; cast weights -> wqb, wob bf16
// ---------------------------------------------------------------------------
__global__ __launch_bounds__(256) void k_cast(
    const float* __restrict__ x, const float* __restrict__ qkv_w,
    const float* __restrict__ out_w, unsigned short* __restrict__ xbT,
    unsigned short* __restrict__ wqb, unsigned short* __restrict__ wob) {
  int bid = blockIdx.x, t = threadIdx.x;
  if (bid < 2048) {
    __shared__ float Lt[64][65];
    int b = bid >> 10, rest = bid & 1023, ct = rest >> 8, pt = rest & 255;
    const float* xp = x + ((size_t)b * 256 + ct * 64) * HWN + pt * 64;
    for (int it = 0; it < 16; ++it) {
      int idx = it * 256 + t; int cc = idx >> 6, pp = idx & 63;
      Lt[cc][pp] = xp[(size_t)cc * HWN + pp];
    }
    __syncthreads();
    int prow = t >> 2, c0 = (t & 3) * 16;
    unsigned short* dst = xbT + ((size_t)b * HWN + pt * 64 + prow) * 256 + ct * 64 + c0;
    ushort8v o1, o2;
#pragma unroll
    for (int q = 0; q < 8; ++q) o1[q] = f2bu(Lt[c0 + q][prow]);
#pragma unroll
    for (int q = 0; q < 8; ++q) o2[q] = f2bu(Lt[c0 + 8 + q][prow]);
    *(ushort8v*)dst = o1;
    *(ushort8v*)(dst + 8) = o2;
  } else {
    int base = (bid - 2048) * 1024 + t * 4;
    if (base < 98304) {
      float4 v = *(const float4*)(qkv_w + base);
      ushort4v o; o[0]=f2bu(v.x); o[1]=f2bu(v.y); o[2]=f2bu(v.z); o[3]=f2bu(v.w);
      *(ushort4v*)(wqb + base) = o;
    } else {
      int b2 = base - 98304;
      float4 v = *(const float4*)(out_w + b2);
      ushort4v o; o[0]=f2bu(v.x); o[1]=f2bu(v.y); o[2]=f2bu(v.z); o[3]=f2bu(v.w);
      *(ushort4v*)(wob + b2) = o;
    }
  }
}

// ---------------------------------------------------------------------------
// K1: qkv[b][o][p] = sum_c wqb[o][c]*xbT[p][c] + bias (MFMA) -> qkvb bf16
//     also writes kT[bg][p][32] (K channels transposed) when ot==1
// ---------------------------------------------------------------------------
__global__ __launch_bounds__(256) void k_qkv(
    const unsigned short* __restrict__ wqb, const unsigned short* __restrict__ xbT,
    const float* __restrict__ qkv_b, unsigned short* __restrict__ qkvb,
    unsigned short* __restrict__ kT) {
  int pt = blockIdx.x, ot = blockIdx.y, b = blockIdx.z;
  int tid = threadIdx.x, w = tid >> 6, lane = tid & 63;
  int lg = lane >> 4, ln = lane & 15;
  f32x4 acc[4] = {};
  const int orow = ot * 64 + w * 16 + ln;
#pragma unroll
  for (int ks = 0; ks < 8; ++ks) {
    int c0 = ks * 32;
    bf16x8 aw = *(const bf16x8*)(wqb + (size_t)orow * 256 + c0 + lg * 8);
#pragma unroll
    for (int nt = 0; nt < 4; ++nt) {
      bf16x8 bx = *(const bf16x8*)(xbT + ((size_t)b * HWN + pt * 64 + nt * 16 + ln) * 256 + c0 + lg * 8);
      acc[nt] = MFMA16(aw, bx, acc[nt]);
    }
  }
#pragma unroll
  for (int nt = 0; nt < 4; ++nt) {
    int p = pt * 64 + nt * 16 + ln;
    ushort4v vals;
#pragma unroll
    for (int r = 0; r < 4; ++r) {
      int o = ot * 64 + w * 16 + lg * 4 + r;
      vals[r] = f2bu(acc[nt][r] + qkv_b[o]);
      qkvb[((size_t)b * 384 + o) * HWN + p] = vals[r];
    }
    if (ot == 1) {   // K channels: o-64 = w*16+lg*4+r -> g=w>>1, d=(w&1)*16+lg*4+r
      int bgi = b * 2 + (w >> 1);
      int d0 = (w & 1) * 16 + lg * 4;
      *(ushort4v*)(kT + ((size_t)bgi * HWN + p) * 32 + d0) = vals;
    }
  }
}

// ---------------------------------------------------------------------------
// K2: 4x4 avg pool -> qpb[bg][32 d][1024 i] bf16, kpt[bg][1024 i][32 d] bf16
// ---------------------------------------------------------------------------
__global__ __launch_bounds__(256) void k_pool(
    const unsigned short* __restrict__ qkvb, unsigned short* __restrict__ qpb,
    unsigned short* __restrict__ kpt) {
  int idx = blockIdx.x * 256 + threadIdx.x;   // 131072
  int i1 = idx & 1023, cc = (idx >> 10) & 31, bg = idx >> 15;
  int b = bg >> 1, g = bg & 1;
  int h1 = i1 >> 5, w1 = i1 & 31;
  const unsigned short* bq = qkvb + (size_t)(b * 384 + g * 32 + cc) * HWN;
  const unsigned short* bk = qkvb + (size_t)(b * 384 + 64 + g * 32 + cc) * HWN;
  float sq = 0.f, sk = 0.f;
#pragma unroll
  for (int sh = 0; sh < 4; ++sh) {
    int off = (h1 * 4 + sh) * 128 + w1 * 4;
    ushort4v vq = *(const ushort4v*)(bq + off);
    ushort4v vk = *(const ushort4v*)(bk + off);
#pragma unroll
    for (int e = 0; e < 4; ++e) { sq += b2f(vq[e]); sk += b2f(vk[e]); }
  }
  qpb[((size_t)bg * 32 + cc) * NP1 + i1] = f2bu(sq * 0.0625f);
  kpt[((size_t)bg * NP1 + i1) * 32 + cc] = f2bu(sk * 0.0625f);
}

// ---------------------------------------------------------------------------
// K3: scores of A_m, single pass: Eut[bg][j][i] = bf16(exp(k_i . q_j)),
//     lpart[bg][ic][j] = partial column sums (of the ROUNDED values).
// grid (jt 16, ic 4, bg 4)
// ---------------------------------------------------------------------------
__global__ __launch_bounds__(256) void k_score(
    const unsigned short* __restrict__ qpb, const unsigned short* __restrict__ kpt,
    unsigned short* __restrict__ Eut, float* __restrict__ lpart) {
  int jt = blockIdx.x, ic = blockIdx.y, bg = blockIdx.z;
  int tid = threadIdx.x, w = tid >> 6, lane = tid & 63;
  int lg = lane >> 4, ln = lane & 15;
  __shared__ float redL[4][64];
  bf16x8 bq[4];
#pragma unroll
  for (int nt = 0; nt < 4; ++nt) {
    ushort8v t8;
#pragma unroll
    for (int jr = 0; jr < 8; ++jr)
      t8[jr] = qpb[((size_t)bg * 32 + lg * 8 + jr) * NP1 + jt * 64 + nt * 16 + ln];
    bq[nt] = scale_l2e(t8);
  }
  float lsum[4] = {0.f, 0.f, 0.f, 0.f};
  for (int chk = 0; chk < 4; ++chk) {
    int i0 = ic * 256 + chk * 64;
    bf16x8 ak = *(const bf16x8*)(kpt + ((size_t)bg * NP1 + i0 + w * 16 + ln) * 32 + lg * 8);
#pragma unroll
    for (int nt = 0; nt < 4; ++nt) {
      f32x4 z = {0.f, 0.f, 0.f, 0.f};
      f32x4 s = MFMA16(ak, bq[nt], z);
      int j = jt * 64 + nt * 16 + ln;
      int ib = i0 + w * 16 + lg * 4;
      unsigned short u0 = f2bu(exp2f(s[0]));
      unsigned short u1 = f2bu(exp2f(s[1]));
      unsigned short u2 = f2bu(exp2f(s[2]));
      unsigned short u3 = f2bu(exp2f(s[3]));
      lsum[nt] += b2f(u0) + b2f(u1) + b2f(u2) + b2f(u3);
      uint2v pk;
      pk[0] = (unsigned)u0 | ((unsigned)u1 << 16);
      pk[1] = (unsigned)u2 | ((unsigned)u3 << 16);
      *(uint2v*)(Eut + ((size_t)bg * NP1 + j) * NP1 + ib) = pk;
    }
  }
#pragma unroll
  for (int nt = 0; nt < 4; ++nt) {
    float v = lsum[nt];
    v += __shfl_xor(v, 16); v += __shfl_xor(v, 32);
    if (lane < 16) redL[w][nt * 16 + lane] = v;
  }
  __syncthreads();
  if (tid < 64)
    lpart[((size_t)(bg * 4 + ic)) * NP1 + jt * 64 + tid] =
        redL[0][tid] + redL[1][tid] + redL[2][tid] + redL[3][tid];
}

// K3b: linv[bg][j] = 1/sum_ic lpart
__global__ __launch_bounds__(256) void k_lsum(
    const float* __restrict__ lpart, float* __restrict__ linv) {
  int gid = blockIdx.x * 256 + threadIdx.x;  // 4096
  int bg = gid >> 10, j = gid & 1023;
  float l = 0.f;
#pragma unroll
  for (int ic = 0; ic < 4; ++ic) l += lpart[((size_t)(bg * 4 + ic)) * NP1 + j];
  linv[gid] = 1.f / l;
}

// K3c: rvec[bg][i] = (A*1)[i] = sum_j Eut[j][i]*linv[j]
__global__ __launch_bounds__(256) void k_rvec(
    const unsigned short* __restrict__ Eut, const float* __restrict__ linv,
    float* __restrict__ rvec) {
  int it = blockIdx.x, bg = blockIdx.y, t = threadIdx.x;
  __shared__ float linv_s[1024];
  __shared__ float red[4][64];
  for (int j = t; j < 1024; j += 256) linv_s[j] = linv[bg * NP1 + j];
  __syncthreads();
  int ii = t & 63, js = t >> 6;
  int i = it * 64 + ii;
  float a = 0.f;
  for (int j = js; j < 1024; j += 4)
    a += b2f(Eut[((size_t)bg * NP1 + j) * NP1 + i]) * linv_s[j];
  red[js][ii] = a;
  __syncthreads();
  if (t < 64) rvec[(size_t)bg * NP1 + it * 64 + t] =
      red[0][t] + red[1][t] + red[2][t] + red[3][t];
}

// ---------------------------------------------------------------------------
// K4: flash W1 = Vf @ exp(Kf^T q) (max-free), split-K 16 partials (MFMA)
// grid (jt 16, kc 16, bg 4)
// ---------------------------------------------------------------------------
__global__ __launch_bounds__(256) void k_flashW1(
    const unsigned short* __restrict__ qkvb, const unsigned short* __restrict__ kT,
    const unsigned short* __restrict__ qpb,
    float* __restrict__ pacc, float* __restrict__ pl) {
  int jt = blockIdx.x, kc = blockIdx.y, bg = blockIdx.z;
  int b = bg >> 1, g = bg & 1;
  int tid = threadIdx.x, w = tid >> 6, lane = tid & 63;
  int lg = lane >> 4, ln = lane & 15;
  __shared__ unsigned short PtS[64 * 64];
  __shared__ float redL[4][64];
  const int Vch = b * 384 + 128 + g * 128;
  bf16x8 bq[4];
#pragma unroll
  for (int nt = 0; nt < 4; ++nt) {
    ushort8v t8;
#pragma unroll
    for (int jr = 0; jr < 8; ++jr)
      t8[jr] = qpb[((size_t)bg * 32 + lg * 8 + jr) * NP1 + jt * 64 + nt * 16 + ln];
    bq[nt] = scale_l2e(t8);
  }
  f32x4 acc[2][4] = {};
  float lsum[4] = {0.f, 0.f, 0.f, 0.f};
  for (int chk = 0; chk < 16; ++chk) {
    int i0 = kc * 1024 + chk * 64;
    bf16x8 ak = *(const bf16x8*)(kT + ((size_t)bg * HWN + i0 + w * 16 + ln) * 32 + lg * 8);
    float e[4][4];
#pragma unroll
    for (int nt = 0; nt < 4; ++nt) {
      f32x4 z = {0.f, 0.f, 0.f, 0.f};
      f32x4 s = MFMA16(ak, bq[nt], z);
#pragma unroll
      for (int r = 0; r < 4; ++r) { e[nt][r] = exp2f(s[r]); lsum[nt] += e[nt][r]; }
    }
    __syncthreads();   // previous PV readers of PtS done
#pragma unroll
    for (int nt = 0; nt < 4; ++nt) {
      uint2v pk;
      pk[0] = (unsigned)f2bu(e[nt][0]) | ((unsigned)f2bu(e[nt][1]) << 16);
      pk[1] = (unsigned)f2bu(e[nt][2]) | ((unsigned)f2bu(e[nt][3]) << 16);
      *(uint2v*)&PtS[PIDX(nt * 16 + ln, w * 16 + lg * 4)] = pk;
    }
    __syncthreads();   // P visible
#pragma unroll
    for (int ist = 0; ist < 2; ++ist) {
      bf16x8 bp[4];
#pragma unroll
      for (int nt = 0; nt < 4; ++nt)
        bp[nt] = *(const bf16x8*)&PtS[PIDX(nt * 16 + ln, ist * 32 + lg * 8)];
#pragma unroll
      for (int ct = 0; ct < 2; ++ct) {
        bf16x8 av = *(const bf16x8*)(qkvb + (size_t)(Vch + w * 32 + ct * 16 + ln) * HWN + i0 + ist * 32 + lg * 8);
#pragma unroll
        for (int nt = 0; nt < 4; ++nt)
          acc[ct][nt] = MFMA16(av, bp[nt], acc[ct][nt]);
      }
    }
  }
  size_t pb = (((size_t)bg * 16 + jt) * 16 + kc) * 8192;
#pragma unroll
  for (int ct = 0; ct < 2; ++ct)
#pragma unroll
    for (int nt = 0; nt < 4; ++nt)
#pragma unroll
      for (int r = 0; r < 4; ++r)
        pacc[pb + (size_t)(w * 32 + ct * 16 + lg * 4 + r) * 64 + nt * 16 + ln] = acc[ct][nt][r];
#pragma unroll
  for (int nt = 0; nt < 4; ++nt) {
    float v = lsum[nt];
    v += __shfl_xor(v, 16); v += __shfl_xor(v, 32);
    if (lane < 16) redL[w][nt * 16 + lane] = v;
  }
  __syncthreads();
  if (tid < 64)
    pl[(((size_t)bg * 16 + jt) * 16 + kc) * 64 + tid] =
        redL[0][tid] + redL[1][tid] + redL[2][tid] + redL[3][tid];
}

// ---------------------------------------------------------------------------
// K5: combine split-K partials -> Yf = W1 (f32)
// ---------------------------------------------------------------------------
__global__ __launch_bounds__(256) void k_combine(
    const float* __restrict__ pacc, const float* __restrict__ pl,
    float* __restrict__ Yf) {
  int gid = blockIdx.x * 256 + threadIdx.x;   // 524288
  int bg = gid >> 17, rem = gid & 131071;
  int c = rem >> 10, j = rem & 1023;
  int jt = j >> 6, jj = j & 63;
  float s = 0.f, l = 0.f;
#pragma unroll
  for (int kc = 0; kc < 16; ++kc) {
    size_t pb = ((size_t)bg * 16 + jt) * 16 + kc;
    s += pacc[pb * 8192 + c * 64 + jj];
    l += pl[pb * 64 + jj];
  }
  Yf[gid] = s / l;
}

// ---------------------------------------------------------------------------
// K5b: Perron deflation: c = (y.r)/(1.r); Yf := Y - c/2 (f32, W2 accumulator),
//      U0b := bf16(Y - c).  grid (ct 2, bg 4)
// ---------------------------------------------------------------------------
__global__ __launch_bounds__(256) void k_proj(
    const float* __restrict__ rvec, float* __restrict__ Yf,
    unsigned short* __restrict__ U0b) {
  int ct = blockIdx.x, bg = blockIdx.y, t = threadIdx.x;
  __shared__ float red[256];
  __shared__ float crow[64];
  __shared__ float sS;
  float p = 0.f;
  for (int j = t; j < 1024; j += 256) p += rvec[(size_t)bg * NP1 + j];
  red[t] = p; __syncthreads();
  for (int s = 128; s > 0; s >>= 1) {
    if (t < s) red[t] += red[t + s];
    __syncthreads();
  }
  if (t == 0) sS = red[0];
  __syncthreads();
  int row = t & 63, js = t >> 6;
  const float* yrow = Yf + ((size_t)(bg * 128 + ct * 64 + row)) * NP1;
  float a = 0.f;
  for (int j = js; j < 1024; j += 4) a += yrow[j] * rvec[(size_t)bg * NP1 + j];
  __syncthreads();
  red[js * 64 + row] = a; __syncthreads();
  if (t < 64) crow[t] = (red[t] + red[64 + t] + red[128 + t] + red[192 + t]) / sS;
  __syncthreads();
  for (int e = t; e < 64 * 1024; e += 256) {
    int rr = e >> 10, j = e & 1023;
    size_t o = ((size_t)(bg * 128 + ct * 64 + rr)) * NP1 + j;
    float y = Yf[o], cv = crow[rr];
    Yf[o] = y - 0.5f * cv;
    U0b[o] = f2bu(y - cv);
  }
}

// ---------------------------------------------------------------------------
// K6: series step: V' = (Vin . Eut)*linv[j];  W2f += sgn*V' ;
//     last: W2b = bf16(W2f + sgn*V').  grid (jt 32, ct 2, bg 4)
// ---------------------------------------------------------------------------
__global__ __launch_bounds__(256) void k_neu(
    const unsigned short* __restrict__ Vin, const unsigned short* __restrict__ Eut,
    const float* __restrict__ linv, float* __restrict__ W2f,
    unsigned short* __restrict__ Vout, unsigned short* __restrict__ W2b,
    float sgn, int last) {
  int jt = blockIdx.x, ct = blockIdx.y, bg = blockIdx.z;
  int tid = threadIdx.x, w = tid >> 6, lane = tid & 63;
  int lg = lane >> 4, ln = lane & 15;
  int j0 = jt * 32, c0 = ct * 64 + w * 16;
  f32x4 acc[2] = {};
  for (int ks = 0; ks < 32; ++ks) {
    int i0 = ks * 32;
    bf16x8 a = *(const bf16x8*)(Vin + ((size_t)(bg * 128) + c0 + ln) * NP1 + i0 + lg * 8);
#pragma unroll
    for (int nt = 0; nt < 2; ++nt) {
      bf16x8 bt = *(const bf16x8*)(Eut + ((size_t)bg * NP1 + j0 + nt * 16 + ln) * NP1 + i0 + lg * 8);
      acc[nt] = MFMA16(a, bt, acc[nt]);
    }
  }
#pragma unroll
  for (int nt = 0; nt < 2; ++nt) {
    int j = j0 + nt * 16 + ln;
    float li = linv[(size_t)bg * NP1 + j];
#pragma unroll
    for (int r = 0; r < 4; ++r) {
      size_t o = ((size_t)(bg * 128) + c0 + lg * 4 + r) * NP1 + j;
      float v = acc[nt][r] * li;
      if (last) W2b[o] = f2bu(W2f[o] + sgn * v);
      else { Vout[o] = f2bu(v); W2f[o] += sgn * v; }
    }
  }
}

// ---------------------------------------------------------------------------
// K7: flash O = W2 @ exp(k^T Qf)/l + W2[:,i1(j)]   (full M^-1 in W2; no 0.5)
// grid (jt 256, bg 4); writes Ot[b][p][c] bf16
// ---------------------------------------------------------------------------
__global__ __launch_bounds__(256) void k_flashO(
    const unsigned short* __restrict__ qkvb, const unsigned short* __restrict__ kpt,
    const unsigned short* __restrict__ W2b, unsigned short* __restrict__ Ot) {
  int jt = blockIdx.x, bg = blockIdx.y;
  int b = bg >> 1, g = bg & 1;
  int tid = threadIdx.x, w = tid >> 6, lane = tid & 63;
  int lg = lane >> 4, ln = lane & 15;
  __shared__ unsigned short PtS[64 * 64];
  __shared__ float redL[4][64];
  __shared__ float smL[64];
  const int Qch = b * 384 + g * 32;
  bf16x8 bq[4];
#pragma unroll
  for (int nt = 0; nt < 4; ++nt) {
    ushort8v t8;
#pragma unroll
    for (int jr = 0; jr < 8; ++jr)
      t8[jr] = qkvb[(size_t)(Qch + lg * 8 + jr) * HWN + jt * 64 + nt * 16 + ln];
    bq[nt] = scale_l2e(t8);
  }
  f32x4 acc[2][4] = {};
  float lsum[4] = {0.f, 0.f, 0.f, 0.f};
  for (int chk = 0; chk < 16; ++chk) {
    int i0 = chk * 64;
    bf16x8 ak = *(const bf16x8*)(kpt + ((size_t)bg * NP1 + i0 + w * 16 + ln) * 32 + lg * 8);
    float e[4][4];
#pragma unroll
    for (int nt = 0; nt < 4; ++nt) {
      f32x4 z = {0.f, 0.f, 0.f, 0.f};
      f32x4 s = MFMA16(ak, bq[nt], z);
#pragma unroll
      for (int r = 0; r < 4; ++r) { e[nt][r] = exp2f(s[r]); lsum[nt] += e[nt][r]; }
    }
    __syncthreads();
#pragma unroll
    for (int nt = 0; nt < 4; ++nt) {
      uint2v pk;
      pk[0] = (unsigned)f2bu(e[nt][0]) | ((unsigned)f2bu(e[nt][1]) << 16);
      pk[1] = (unsigned)f2bu(e[nt][2]) | ((unsigned)f2bu(e[nt][3]) << 16);
      *(uint2v*)&PtS[PIDX(nt * 16 + ln, w * 16 + lg * 4)] = pk;
    }
    __syncthreads();
#pragma unroll
    for (int ist = 0; ist < 2; ++ist) {
      bf16x8 bp[4];
#pragma unroll
      for (int nt = 0; nt < 4; ++nt)
        bp[nt] = *(const bf16x8*)&PtS[PIDX(nt * 16 + ln, ist * 32 + lg * 8)];
#pragma unroll
      for (int ct = 0; ct < 2; ++ct) {
        bf16x8 av = *(const bf16x8*)(W2b + ((size_t)bg * 128 + w * 32 + ct * 16 + ln) * NP1 + i0 + ist * 32 + lg * 8);
#pragma unroll
        for (int nt = 0; nt < 4; ++nt)
          acc[ct][nt] = MFMA16(av, bp[nt], acc[ct][nt]);
      }
    }
  }
#pragma unroll
  for (int nt = 0; nt < 4; ++nt) {
    float v = lsum[nt];
    v += __shfl_xor(v, 16); v += __shfl_xor(v, 32);
    if (lane < 16) redL[w][nt * 16 + lane] = v;
  }
  __syncthreads();
  if (tid < 64) smL[tid] = redL[0][tid] + redL[1][tid] + redL[2][tid] + redL[3][tid];
  __syncthreads();
#pragma unroll
  for (int nt = 0; nt < 4; ++nt) {
    int jj = nt * 16 + ln;
    int jg = jt * 64 + jj;
    float linv = 1.f / smL[jj];
    int i1 = (jg >> 9) * 32 + ((jg & 127) >> 2);
#pragma unroll
    for (int ct = 0; ct < 2; ++ct) {
      ushort4v o4;
#pragma unroll
      for (int r = 0; r < 4; ++r) {
        int c = w * 32 + ct * 16 + lg * 4 + r;
        float v = acc[ct][nt][r] * linv + b2f(W2b[((size_t)bg * 128 + c) * NP1 + i1]);
        o4[r] = f2bu(v);
      }
      *(ushort4v*)(Ot + ((size_t)b * HWN + jg) * 256 + g * 128 + w * 32 + ct * 16 + lg * 4) = o4;
    }
  }
}

// ---------------------------------------------------------------------------
// K8: out = gamma * (wob @ Ot + out_b) + x  (MFMA, f32 epilogue)
// ---------------------------------------------------------------------------
__global__ __launch_bounds__(256) void k_out(
    const unsigned short* __restrict__ wob, const unsigned short* __restrict__ Ot,
    const float* __restrict__ out_b, const float* __restrict__ x,
    const float* __restrict__ gamma, const int* __restrict__ mode,
    float* __restrict__ out) {
  int pt = blockIdx.x, ot = blockIdx.y, b = blockIdx.z;
  int tid = threadIdx.x, w = tid >> 6, lane = tid & 63;
  int lg = lane >> 4, ln = lane & 15;
  f32x4 acc[4] = {};
  const int orow = ot * 64 + w * 16 + ln;
#pragma unroll
  for (int ks = 0; ks < 8; ++ks) {
    int c0 = ks * 32;
    bf16x8 aw = *(const bf16x8*)(wob + (size_t)orow * 256 + c0 + lg * 8);
#pragma unroll
    for (int nt = 0; nt < 4; ++nt) {
      bf16x8 bx = *(const bf16x8*)(Ot + ((size_t)b * HWN + pt * 64 + nt * 16 + ln) * 256 + c0 + lg * 8);
      acc[nt] = MFMA16(aw, bx, acc[nt]);
    }
  }
  float gm = gamma[0];
  int md = mode[0];
#pragma unroll
  for (int nt = 0; nt < 4; ++nt)
#pragma unroll
    for (int r = 0; r < 4; ++r) {
      int o = ot * 64 + w * 16 + lg * 4 + r;
      int p = pt * 64 + nt * 16 + ln;
      size_t off = ((size_t)b * 256 + o) * HWN + p;
      float v = acc[nt][r] + out_b[o];
      out[off] = (md == 0) ? (gm * v + x[off]) : v;
    }
}

// ---------------------------------------------------------------------------
extern "C" void kernel_launch(void* const* d_in, const int* in_sizes, int n_in,
                              void* d_out, int out_size, void* d_ws, size_t ws_size,
                              hipStream_t stream) {
  (void)in_sizes; (void)n_in; (void)out_size;
  const float* x     = (const float*)d_in[0];
  const float* qkv_w = (const float*)d_in[1];
  const float* qkv_b = (const float*)d_in[2];
  const float* out_w = (const float*)d_in[3];
  const float* out_b = (const float*)d_in[4];
  const float* gamma = (const float*)d_in[5];
  const int*   mode  = (const int*)d_in[6];
  float* out = (float*)d_out;

  char* wsb = (char*)d_ws;
  size_t off = 0;
  auto alloc = [&](size_t bytes) { char* p = wsb + off; off += bytes; return p; };
  unsigned short* xbT  = (unsigned short*)alloc(16777216);  // [2][16384][256]
  unsigned short* wqb  = (unsigned short*)alloc(196608);
  unsigned short* wob  = (unsigned short*)alloc(131072);
  unsigned short* qkvb = (unsigned short*)alloc(25165824);  // [2][384][16384]
  unsigned short* kT   = (unsigned short*)alloc(4194304);   // [4][16384][32]
  unsigned short* qpb  = (unsigned short*)alloc(262144);    // [4][32][1024]
  unsigned short* kpt  = (unsigned short*)alloc(262144);    // [4][1024][32]
  unsigned short* Eut  = (unsigned short*)alloc(8388608);   // [4][1024 j][1024 i]
  float*          lpart= (float*)alloc(65536);              // [4][4][1024]
  float*          linv = (float*)alloc(16384);              // [4][1024]
  float*          rvec = (float*)alloc(16384);              // [4][1024]
  float*          pacc = (float*)alloc(33554432);           // [4][16][16][128][64]
  float*          pl   = (float*)alloc(262144);             // [4][16][16][64]
  float*          Yf   = (float*)alloc(2097152);            // [4][128][1024] (-> W2f)
  unsigned short* U0b  = (unsigned short*)alloc(1048576);
  unsigned short* Va   = (unsigned short*)alloc(1048576);
  unsigned short* Vb   = (unsigned short*)alloc(1048576);
  unsigned short* W2b  = (unsigned short*)alloc(1048576);
  unsigned short* Ot   = (unsigned short*)pacc;             // alias: pacc dead after k_combine
  if (ws_size < off) return;   // ~95.6 MB

  k_cast<<<2208, 256, 0, stream>>>(x, qkv_w, out_w, xbT, wqb, wob);
  k_qkv<<<dim3(256, 6, 2), 256, 0, stream>>>(wqb, xbT, qkv_b, qkvb, kT);
  k_pool<<<512, 256, 0, stream>>>(qkvb, qpb, kpt);
  k_score<<<dim3(16, 4, 4), 256, 0, stream>>>(qpb, kpt, Eut, lpart);
  k_lsum<<<16, 256, 0, stream>>>(lpart, linv);
  k_rvec<<<dim3(16, 4), 256, 0, stream>>>(Eut, linv, rvec);
  k_flashW1<<<dim3(16, 16, 4), 256, 0, stream>>>(qkvb, kT, qpb, pacc, pl);
  k_combine<<<2048, 256, 0, stream>>>(pacc, pl, Yf);
  k_proj<<<dim3(2, 4), 256, 0, stream>>>(rvec, Yf, U0b);
  k_neu<<<dim3(32, 2, 4), 256, 0, stream>>>(U0b, Eut, linv, Yf, Va, W2b, -1.f, 0);
  k_neu<<<dim3(32, 2, 4), 256, 0, stream>>>(Va,  Eut, linv, Yf, Vb, W2b, +1.f, 0);
  k_neu<<<dim3(32, 2, 4), 256, 0, stream>>>(Vb,  Eut, linv, Yf, Va, W2b, -1.f, 1);
  k_flashO<<<dim3(256, 4), 256, 0, stream>>>(qkvb, kpt, W2b, Ot);
  k_out<<<dim3(256, 4, 2), 256, 0, stream>>>(wob, Ot, out_b, x, gamma, mode, out);
}

// Round 4
// 369.639 us; speedup vs baseline: 9.7046x; 1.2037x over previous
//
#include <hip/hip_runtime.h>
#include <cstdint>
#include <cstddef>

#define HWN 16384   // H*W
#define NP1 1024    // pooled positions
#define RL2E 1.44269504f

typedef __attribute__((ext_vector_type(8))) short bf16x8;            // MFMA A/B frag
typedef __attribute__((ext_vector_type(8))) unsigned short ushort8v;
typedef __attribute__((ext_vector_type(4))) unsigned short ushort4v;
typedef __attribute__((ext_vector_type(2))) unsigned int uint2v;
typedef __attribute__((ext_vector_type(4))) unsigned int uint4v;
typedef __attribute__((ext_vector_type(4))) float f32x4;

__device__ __forceinline__ unsigned short f2bu(float f) {
  unsigned int u = __builtin_bit_cast(unsigned int, f);
  u = (u + 0x7FFFu + ((u >> 16) & 1u)) >> 16;   // RNE
  return (unsigned short)u;
}
__device__ __forceinline__ float b2f(unsigned short s) {
  unsigned int u = ((unsigned int)s) << 16;
  return __builtin_bit_cast(float, u);
}
// HW packed f32->bf16 (RNE): D.lo = bf16(S0), D.hi = bf16(S1)
__device__ __forceinline__ unsigned cvtpk(float lo, float hi) {
  unsigned r;
  asm("v_cvt_pk_bf16_f32 %0, %1, %2" : "=v"(r) : "v"(lo), "v"(hi));
  return r;
}
__device__ __forceinline__ bf16x8 scale_l2e(ushort8v t) {   // q-frag prescale by log2(e)
  ushort8v o;
#pragma unroll
  for (int q = 0; q < 8; ++q) o[q] = f2bu(RL2E * b2f(t[q]));
  return __builtin_bit_cast(bf16x8, o);
}
#define MFMA16(A,B,C) __builtin_amdgcn_mfma_f32_16x16x32_bf16((A),(B),(C),0,0,0)
// XOR-swizzled index (ushort units) for the 64x64 bf16 P tile: byte ^= (row&7)<<4
#define PIDX(r,c) ((((r) << 6) + (c)) ^ (((r) & 7) << 3))

// ---------------------------------------------------------------------------
// K0: cast+transpose x -> xbT[b][p][c] bf16 ; cast weights -> wqb, wob bf16
// ---------------------------------------------------------------------------
__global__ __launch_bounds__(256) void k_cast(
    const float* __restrict__ x, const float* __restrict__ qkv_w,
    const float* __restrict__ out_w, unsigned short* __restrict__ xbT,
    unsigned short* __restrict__ wqb, unsigned short* __restrict__ wob) {
  int bid = blockIdx.x, t = threadIdx.x;
  if (bid < 2048) {
    __shared__ float Lt[64][65];
    int b = bid >> 10, rest = bid & 1023, ct = rest >> 8, pt = rest & 255;
    const float* xp = x + ((size_t)b * 256 + ct * 64) * HWN + pt * 64;
    for (int it = 0; it < 16; ++it) {
      int idx = it * 256 + t; int cc = idx >> 6, pp = idx & 63;
      Lt[cc][pp] = xp[(size_t)cc * HWN + pp];
    }
    __syncthreads();
    int prow = t >> 2, c0 = (t & 3) * 16;
    unsigned short* dst = xbT + ((size_t)b * HWN + pt * 64 + prow) * 256 + ct * 64 + c0;
    uint4v o1, o2;
#pragma unroll
    for (int q = 0; q < 4; ++q) o1[q] = cvtpk(Lt[c0 + 2*q][prow], Lt[c0 + 2*q + 1][prow]);
#pragma unroll
    for (int q = 0; q < 4; ++q) o2[q] = cvtpk(Lt[c0 + 8 + 2*q][prow], Lt[c0 + 9 + 2*q][prow]);
    *(uint4v*)dst = o1;
    *(uint4v*)(dst + 8) = o2;
  } else {
    int base = (bid - 2048) * 1024 + t * 4;
    if (base < 98304) {
      float4 v = *(const float4*)(qkv_w + base);
      uint2v o; o[0] = cvtpk(v.x, v.y); o[1] = cvtpk(v.z, v.w);
      *(uint2v*)(wqb + base) = o;
    } else {
      int b2 = base - 98304;
      float4 v = *(const float4*)(out_w + b2);
      uint2v o; o[0] = cvtpk(v.x, v.y); o[1] = cvtpk(v.z, v.w);
      *(uint2v*)(wob + b2) = o;
    }
  }
}

// ---------------------------------------------------------------------------
// K1: qkv[b][o][p] = sum_c wqb[o][c]*xbT[p][c] + bias (MFMA) -> qkvb bf16
//     also writes kT[bg][p][32] (K channels transposed) when ot==1
// ---------------------------------------------------------------------------
__global__ __launch_bounds__(256) void k_qkv(
    const unsigned short* __restrict__ wqb, const unsigned short* __restrict__ xbT,
    const float* __restrict__ qkv_b, unsigned short* __restrict__ qkvb,
    unsigned short* __restrict__ kT) {
  int pt = blockIdx.x, ot = blockIdx.y, b = blockIdx.z;
  int tid = threadIdx.x, w = tid >> 6, lane = tid & 63;
  int lg = lane >> 4, ln = lane & 15;
  f32x4 acc[4] = {};
  const int orow = ot * 64 + w * 16 + ln;
#pragma unroll
  for (int ks = 0; ks < 8; ++ks) {
    int c0 = ks * 32;
    bf16x8 aw = *(const bf16x8*)(wqb + (size_t)orow * 256 + c0 + lg * 8);
#pragma unroll
    for (int nt = 0; nt < 4; ++nt) {
      bf16x8 bx = *(const bf16x8*)(xbT + ((size_t)b * HWN + pt * 64 + nt * 16 + ln) * 256 + c0 + lg * 8);
      acc[nt] = MFMA16(aw, bx, acc[nt]);
    }
  }
  int ob = ot * 64 + w * 16 + lg * 4;
  float b0 = qkv_b[ob], b1 = qkv_b[ob + 1], b2 = qkv_b[ob + 2], b3 = qkv_b[ob + 3];
#pragma unroll
  for (int nt = 0; nt < 4; ++nt) {
    int p = pt * 64 + nt * 16 + ln;
    unsigned u01 = cvtpk(acc[nt][0] + b0, acc[nt][1] + b1);
    unsigned u23 = cvtpk(acc[nt][2] + b2, acc[nt][3] + b3);
    size_t qb = ((size_t)b * 384 + ob) * HWN + p;
    qkvb[qb]           = (unsigned short)u01;
    qkvb[qb + HWN]     = (unsigned short)(u01 >> 16);
    qkvb[qb + 2 * HWN] = (unsigned short)u23;
    qkvb[qb + 3 * HWN] = (unsigned short)(u23 >> 16);
    if (ot == 1) {   // K channels: g=w>>1, d=(w&1)*16+lg*4
      int bgi = b * 2 + (w >> 1);
      int d0 = (w & 1) * 16 + lg * 4;
      uint2v kv; kv[0] = u01; kv[1] = u23;
      *(uint2v*)(kT + ((size_t)bgi * HWN + p) * 32 + d0) = kv;
    }
  }
}

// ---------------------------------------------------------------------------
// K2: 4x4 avg pool -> qpb[bg][32 d][1024 i] bf16, kpt[bg][1024 i][32 d] bf16
// ---------------------------------------------------------------------------
__global__ __launch_bounds__(256) void k_pool(
    const unsigned short* __restrict__ qkvb, unsigned short* __restrict__ qpb,
    unsigned short* __restrict__ kpt) {
  int idx = blockIdx.x * 256 + threadIdx.x;   // 131072
  int i1 = idx & 1023, cc = (idx >> 10) & 31, bg = idx >> 15;
  int b = bg >> 1, g = bg & 1;
  int h1 = i1 >> 5, w1 = i1 & 31;
  const unsigned short* bq = qkvb + (size_t)(b * 384 + g * 32 + cc) * HWN;
  const unsigned short* bk = qkvb + (size_t)(b * 384 + 64 + g * 32 + cc) * HWN;
  float sq = 0.f, sk = 0.f;
#pragma unroll
  for (int sh = 0; sh < 4; ++sh) {
    int off = (h1 * 4 + sh) * 128 + w1 * 4;
    ushort4v vq = *(const ushort4v*)(bq + off);
    ushort4v vk = *(const ushort4v*)(bk + off);
#pragma unroll
    for (int e = 0; e < 4; ++e) { sq += b2f(vq[e]); sk += b2f(vk[e]); }
  }
  qpb[((size_t)bg * 32 + cc) * NP1 + i1] = f2bu(sq * 0.0625f);
  kpt[((size_t)bg * NP1 + i1) * 32 + cc] = f2bu(sk * 0.0625f);
}

// ---------------------------------------------------------------------------
// K3: scores of A_m, single pass: Eut[bg][j][i] = bf16(exp(k_i . q_j)),
//     lpart[bg][ic][j] = partial column sums (pre-rounding f32).
// grid (jt 16, ic 4, bg 4)
// ---------------------------------------------------------------------------
__global__ __launch_bounds__(256) void k_score(
    const unsigned short* __restrict__ qpb, const unsigned short* __restrict__ kpt,
    unsigned short* __restrict__ Eut, float* __restrict__ lpart) {
  int jt = blockIdx.x, ic = blockIdx.y, bg = blockIdx.z;
  int tid = threadIdx.x, w = tid >> 6, lane = tid & 63;
  int lg = lane >> 4, ln = lane & 15;
  __shared__ float redL[4][64];
  bf16x8 bq[4];
#pragma unroll
  for (int nt = 0; nt < 4; ++nt) {
    ushort8v t8;
#pragma unroll
    for (int jr = 0; jr < 8; ++jr)
      t8[jr] = qpb[((size_t)bg * 32 + lg * 8 + jr) * NP1 + jt * 64 + nt * 16 + ln];
    bq[nt] = scale_l2e(t8);
  }
  float lsum[4] = {0.f, 0.f, 0.f, 0.f};
  for (int chk = 0; chk < 4; ++chk) {
    int i0 = ic * 256 + chk * 64;
    bf16x8 ak = *(const bf16x8*)(kpt + ((size_t)bg * NP1 + i0 + w * 16 + ln) * 32 + lg * 8);
#pragma unroll
    for (int nt = 0; nt < 4; ++nt) {
      f32x4 z = {0.f, 0.f, 0.f, 0.f};
      f32x4 s = MFMA16(ak, bq[nt], z);
      float e0 = exp2f(s[0]), e1 = exp2f(s[1]), e2 = exp2f(s[2]), e3 = exp2f(s[3]);
      lsum[nt] += (e0 + e1) + (e2 + e3);
      int j = jt * 64 + nt * 16 + ln;
      int ib = i0 + w * 16 + lg * 4;
      uint2v pk;
      pk[0] = cvtpk(e0, e1);
      pk[1] = cvtpk(e2, e3);
      *(uint2v*)(Eut + ((size_t)bg * NP1 + j) * NP1 + ib) = pk;
    }
  }
#pragma unroll
  for (int nt = 0; nt < 4; ++nt) {
    float v = lsum[nt];
    v += __shfl_xor(v, 16); v += __shfl_xor(v, 32);
    if (lane < 16) redL[w][nt * 16 + lane] = v;
  }
  __syncthreads();
  if (tid < 64)
    lpart[((size_t)(bg * 4 + ic)) * NP1 + jt * 64 + tid] =
        redL[0][tid] + redL[1][tid] + redL[2][tid] + redL[3][tid];
}

// ---------------------------------------------------------------------------
// K3b: linv (from lpart) + rvec[bg][i] = sum_j Eut[j][i]*linv[j]
// grid (it 16, bg 4); block it==0 also writes linv to global
// ---------------------------------------------------------------------------
__global__ __launch_bounds__(256) void k_rvec(
    const unsigned short* __restrict__ Eut, const float* __restrict__ lpart,
    float* __restrict__ linv, float* __restrict__ rvec) {
  int it = blockIdx.x, bg = blockIdx.y, t = threadIdx.x;
  __shared__ float linv_s[1024];
  __shared__ float red[4][64];
  for (int j = t; j < 1024; j += 256) {
    float l = 0.f;
#pragma unroll
    for (int ic = 0; ic < 4; ++ic) l += lpart[((size_t)(bg * 4 + ic)) * NP1 + j];
    float inv = 1.f / l;
    linv_s[j] = inv;
    if (it == 0) linv[(size_t)bg * NP1 + j] = inv;
  }
  __syncthreads();
  int ii = t & 63, js = t >> 6;
  int i = it * 64 + ii;
  float a = 0.f;
  for (int j = js; j < 1024; j += 4)
    a += b2f(Eut[((size_t)bg * NP1 + j) * NP1 + i]) * linv_s[j];
  red[js][ii] = a;
  __syncthreads();
  if (t < 64) rvec[(size_t)bg * NP1 + it * 64 + t] =
      red[0][t] + red[1][t] + red[2][t] + red[3][t];
}

// ---------------------------------------------------------------------------
// K4: flash W1 = Vf @ exp(Kf^T q) (max-free), split-K 8 partials (MFMA)
// grid (jt 16, kc 8, bg 4)
// ---------------------------------------------------------------------------
__global__ __launch_bounds__(256) void k_flashW1(
    const unsigned short* __restrict__ qkvb, const unsigned short* __restrict__ kT,
    const unsigned short* __restrict__ qpb,
    float* __restrict__ pacc, float* __restrict__ pl) {
  int jt = blockIdx.x, kc = blockIdx.y, bg = blockIdx.z;
  int b = bg >> 1, g = bg & 1;
  int tid = threadIdx.x, w = tid >> 6, lane = tid & 63;
  int lg = lane >> 4, ln = lane & 15;
  __shared__ unsigned short PtS[64 * 64];
  __shared__ float redL[4][64];
  const int Vch = b * 384 + 128 + g * 128;
  bf16x8 bq[4];
#pragma unroll
  for (int nt = 0; nt < 4; ++nt) {
    ushort8v t8;
#pragma unroll
    for (int jr = 0; jr < 8; ++jr)
      t8[jr] = qpb[((size_t)bg * 32 + lg * 8 + jr) * NP1 + jt * 64 + nt * 16 + ln];
    bq[nt] = scale_l2e(t8);
  }
  f32x4 acc[2][4] = {};
  float lsum[4] = {0.f, 0.f, 0.f, 0.f};
  for (int chk = 0; chk < 32; ++chk) {
    int i0 = kc * 2048 + chk * 64;
    bf16x8 ak = *(const bf16x8*)(kT + ((size_t)bg * HWN + i0 + w * 16 + ln) * 32 + lg * 8);
    float e[4][4];
#pragma unroll
    for (int nt = 0; nt < 4; ++nt) {
      f32x4 z = {0.f, 0.f, 0.f, 0.f};
      f32x4 s = MFMA16(ak, bq[nt], z);
#pragma unroll
      for (int r = 0; r < 4; ++r) e[nt][r] = exp2f(s[r]);
      lsum[nt] += (e[nt][0] + e[nt][1]) + (e[nt][2] + e[nt][3]);
    }
    __syncthreads();   // previous PV readers of PtS done
#pragma unroll
    for (int nt = 0; nt < 4; ++nt) {
      uint2v pk;
      pk[0] = cvtpk(e[nt][0], e[nt][1]);
      pk[1] = cvtpk(e[nt][2], e[nt][3]);
      *(uint2v*)&PtS[PIDX(nt * 16 + ln, w * 16 + lg * 4)] = pk;
    }
    __syncthreads();   // P visible
#pragma unroll
    for (int ist = 0; ist < 2; ++ist) {
      bf16x8 bp[4];
#pragma unroll
      for (int nt = 0; nt < 4; ++nt)
        bp[nt] = *(const bf16x8*)&PtS[PIDX(nt * 16 + ln, ist * 32 + lg * 8)];
#pragma unroll
      for (int ct = 0; ct < 2; ++ct) {
        bf16x8 av = *(const bf16x8*)(qkvb + (size_t)(Vch + w * 32 + ct * 16 + ln) * HWN + i0 + ist * 32 + lg * 8);
#pragma unroll
        for (int nt = 0; nt < 4; ++nt)
          acc[ct][nt] = MFMA16(av, bp[nt], acc[ct][nt]);
      }
    }
  }
  size_t pb = (((size_t)bg * 16 + jt) * 8 + kc) * 8192;
#pragma unroll
  for (int ct = 0; ct < 2; ++ct)
#pragma unroll
    for (int nt = 0; nt < 4; ++nt)
#pragma unroll
      for (int r = 0; r < 4; ++r)
        pacc[pb + (size_t)(w * 32 + ct * 16 + lg * 4 + r) * 64 + nt * 16 + ln] = acc[ct][nt][r];
#pragma unroll
  for (int nt = 0; nt < 4; ++nt) {
    float v = lsum[nt];
    v += __shfl_xor(v, 16); v += __shfl_xor(v, 32);
    if (lane < 16) redL[w][nt * 16 + lane] = v;
  }
  __syncthreads();
  if (tid < 64)
    pl[(((size_t)bg * 16 + jt) * 8 + kc) * 64 + tid] =
        redL[0][tid] + redL[1][tid] + redL[2][tid] + redL[3][tid];
}

// ---------------------------------------------------------------------------
// K5: combine split-K partials -> Yf = W1 (f32)
// ---------------------------------------------------------------------------
__global__ __launch_bounds__(256) void k_combine(
    const float* __restrict__ pacc, const float* __restrict__ pl,
    float* __restrict__ Yf) {
  int gid = blockIdx.x * 256 + threadIdx.x;   // 524288
  int bg = gid >> 17, rem = gid & 131071;
  int c = rem >> 10, j = rem & 1023;
  int jt = j >> 6, jj = j & 63;
  float s = 0.f, l = 0.f;
#pragma unroll
  for (int kc = 0; kc < 8; ++kc) {
    size_t pb = ((size_t)bg * 16 + jt) * 8 + kc;
    s += pacc[pb * 8192 + c * 64 + jj];
    l += pl[pb * 64 + jj];
  }
  Yf[gid] = s / l;
}

// ---------------------------------------------------------------------------
// K5b: Perron deflation, parallel: c_row = (y.r)/(1.r);
//      Yf := Y - c/2 (f32, W2 accumulator), U0b := bf16(Y - c).
// grid (ct 16, bg 4): each block handles 8 rows
// ---------------------------------------------------------------------------
__global__ __launch_bounds__(256) void k_proj(
    const float* __restrict__ rvec, float* __restrict__ Yf,
    unsigned short* __restrict__ U0b) {
  int ct = blockIdx.x, bg = blockIdx.y, t = threadIdx.x;
  __shared__ float rs[1024];
  __shared__ float red[256];
  __shared__ float crow[8];
  __shared__ float sSs;
  for (int j = t; j < 1024; j += 256) rs[j] = rvec[(size_t)bg * NP1 + j];
  __syncthreads();
  float p = rs[t] + rs[t + 256] + rs[t + 512] + rs[t + 768];
  red[t] = p; __syncthreads();
  for (int s = 128; s > 0; s >>= 1) {
    if (t < s) red[t] += red[t + s];
    __syncthreads();
  }
  if (t == 0) sSs = red[0];
  __syncthreads();
  int row = t >> 5, ln32 = t & 31;
  const float* yrow = Yf + ((size_t)(bg * 128 + ct * 8 + row)) * NP1;
  float a = 0.f;
  for (int j = ln32; j < 1024; j += 32) a += yrow[j] * rs[j];
#pragma unroll
  for (int m = 1; m <= 16; m <<= 1) a += __shfl_xor(a, m, 32);
  if (ln32 == 0) crow[row] = a / sSs;
  __syncthreads();
  for (int e = t; e < 8 * 1024; e += 256) {
    int rr = e >> 10, j = e & 1023;
    size_t o = ((size_t)(bg * 128 + ct * 8 + rr)) * NP1 + j;
    float y = Yf[o], cv = crow[rr];
    Yf[o] = y - 0.5f * cv;
    U0b[o] = f2bu(y - cv);
  }
}

// ---------------------------------------------------------------------------
// K6: series step: V' = (Vin . Eut)*linv[j];  W2f += sgn*V' ;
//     last: W2b = bf16(W2f + sgn*V').  grid (jt 32, ct 2, bg 4)
// ---------------------------------------------------------------------------
__global__ __launch_bounds__(256) void k_neu(
    const unsigned short* __restrict__ Vin, const unsigned short* __restrict__ Eut,
    const float* __restrict__ linv, float* __restrict__ W2f,
    unsigned short* __restrict__ Vout, unsigned short* __restrict__ W2b,
    float sgn, int last) {
  int jt = blockIdx.x, ct = blockIdx.y, bg = blockIdx.z;
  int tid = threadIdx.x, w = tid >> 6, lane = tid & 63;
  int lg = lane >> 4, ln = lane & 15;
  int j0 = jt * 32, c0 = ct * 64 + w * 16;
  f32x4 acc[2] = {};
  for (int ks = 0; ks < 32; ++ks) {
    int i0 = ks * 32;
    bf16x8 a = *(const bf16x8*)(Vin + ((size_t)(bg * 128) + c0 + ln) * NP1 + i0 + lg * 8);
#pragma unroll
    for (int nt = 0; nt < 2; ++nt) {
      bf16x8 bt = *(const bf16x8*)(Eut + ((size_t)bg * NP1 + j0 + nt * 16 + ln) * NP1 + i0 + lg * 8);
      acc[nt] = MFMA16(a, bt, acc[nt]);
    }
  }
#pragma unroll
  for (int nt = 0; nt < 2; ++nt) {
    int j = j0 + nt * 16 + ln;
    float li = linv[(size_t)bg * NP1 + j];
#pragma unroll
    for (int r = 0; r < 4; ++r) {
      size_t o = ((size_t)(bg * 128) + c0 + lg * 4 + r) * NP1 + j;
      float v = acc[nt][r] * li;
      if (last) W2b[o] = f2bu(W2f[o] + sgn * v);
      else { Vout[o] = f2bu(v); W2f[o] += sgn * v; }
    }
  }
}

// ---------------------------------------------------------------------------
// K7: flash O = W2 @ exp(k^T Qf)/l + W2[:,i1(j)]   (full M^-1 in W2)
// grid (jt 256, bg 4); writes Ot[b][p][c] bf16
// ---------------------------------------------------------------------------
__global__ __launch_bounds__(256) void k_flashO(
    const unsigned short* __restrict__ qkvb, const unsigned short* __restrict__ kpt,
    const unsigned short* __restrict__ W2b, unsigned short* __restrict__ Ot) {
  int jt = blockIdx.x, bg = blockIdx.y;
  int b = bg >> 1, g = bg & 1;
  int tid = threadIdx.x, w = tid >> 6, lane = tid & 63;
  int lg = lane >> 4, ln = lane & 15;
  __shared__ unsigned short PtS[64 * 64];
  __shared__ float redL[4][64];
  __shared__ float smL[64];
  const int Qch = b * 384 + g * 32;
  bf16x8 bq[4];
#pragma unroll
  for (int nt = 0; nt < 4; ++nt) {
    ushort8v t8;
#pragma unroll
    for (int jr = 0; jr < 8; ++jr)
      t8[jr] = qkvb[(size_t)(Qch + lg * 8 + jr) * HWN + jt * 64 + nt * 16 + ln];
    bq[nt] = scale_l2e(t8);
  }
  f32x4 acc[2][4] = {};
  float lsum[4] = {0.f, 0.f, 0.f, 0.f};
  for (int chk = 0; chk < 16; ++chk) {
    int i0 = chk * 64;
    bf16x8 ak = *(const bf16x8*)(kpt + ((size_t)bg * NP1 + i0 + w * 16 + ln) * 32 + lg * 8);
    float e[4][4];
#pragma unroll
    for (int nt = 0; nt < 4; ++nt) {
      f32x4 z = {0.f, 0.f, 0.f, 0.f};
      f32x4 s = MFMA16(ak, bq[nt], z);
#pragma unroll
      for (int r = 0; r < 4; ++r) e[nt][r] = exp2f(s[r]);
      lsum[nt] += (e[nt][0] + e[nt][1]) + (e[nt][2] + e[nt][3]);
    }
    __syncthreads();
#pragma unroll
    for (int nt = 0; nt < 4; ++nt) {
      uint2v pk;
      pk[0] = cvtpk(e[nt][0], e[nt][1]);
      pk[1] = cvtpk(e[nt][2], e[nt][3]);
      *(uint2v*)&PtS[PIDX(nt * 16 + ln, w * 16 + lg * 4)] = pk;
    }
    __syncthreads();
#pragma unroll
    for (int ist = 0; ist < 2; ++ist) {
      bf16x8 bp[4];
#pragma unroll
      for (int nt = 0; nt < 4; ++nt)
        bp[nt] = *(const bf16x8*)&PtS[PIDX(nt * 16 + ln, ist * 32 + lg * 8)];
#pragma unroll
      for (int ct = 0; ct < 2; ++ct) {
        bf16x8 av = *(const bf16x8*)(W2b + ((size_t)bg * 128 + w * 32 + ct * 16 + ln) * NP1 + i0 + ist * 32 + lg * 8);
#pragma unroll
        for (int nt = 0; nt < 4; ++nt)
          acc[ct][nt] = MFMA16(av, bp[nt], acc[ct][nt]);
      }
    }
  }
#pragma unroll
  for (int nt = 0; nt < 4; ++nt) {
    float v = lsum[nt];
    v += __shfl_xor(v, 16); v += __shfl_xor(v, 32);
    if (lane < 16) redL[w][nt * 16 + lane] = v;
  }
  __syncthreads();
  if (tid < 64) smL[tid] = redL[0][tid] + redL[1][tid] + redL[2][tid] + redL[3][tid];
  __syncthreads();
#pragma unroll
  for (int nt = 0; nt < 4; ++nt) {
    int jj = nt * 16 + ln;
    int jg = jt * 64 + jj;
    float li = 1.f / smL[jj];
    int i1 = (jg >> 9) * 32 + ((jg & 127) >> 2);
#pragma unroll
    for (int ct = 0; ct < 2; ++ct) {
      int c = w * 32 + ct * 16 + lg * 4;
      float v0 = acc[ct][nt][0] * li + b2f(W2b[((size_t)bg * 128 + c + 0) * NP1 + i1]);
      float v1 = acc[ct][nt][1] * li + b2f(W2b[((size_t)bg * 128 + c + 1) * NP1 + i1]);
      float v2 = acc[ct][nt][2] * li + b2f(W2b[((size_t)bg * 128 + c + 2) * NP1 + i1]);
      float v3 = acc[ct][nt][3] * li + b2f(W2b[((size_t)bg * 128 + c + 3) * NP1 + i1]);
      uint2v o2; o2[0] = cvtpk(v0, v1); o2[1] = cvtpk(v2, v3);
      *(uint2v*)(Ot + ((size_t)b * HWN + jg) * 256 + g * 128 + c) = o2;
    }
  }
}

// ---------------------------------------------------------------------------
// K8: out = gamma * (wob @ Ot + out_b) + x  (MFMA, f32 epilogue)
// ---------------------------------------------------------------------------
__global__ __launch_bounds__(256) void k_out(
    const unsigned short* __restrict__ wob, const unsigned short* __restrict__ Ot,
    const float* __restrict__ out_b, const float* __restrict__ x,
    const float* __restrict__ gamma, const int* __restrict__ mode,
    float* __restrict__ out) {
  int pt = blockIdx.x, ot = blockIdx.y, b = blockIdx.z;
  int tid = threadIdx.x, w = tid >> 6, lane = tid & 63;
  int lg = lane >> 4, ln = lane & 15;
  f32x4 acc[4] = {};
  const int orow = ot * 64 + w * 16 + ln;
#pragma unroll
  for (int ks = 0; ks < 8; ++ks) {
    int c0 = ks * 32;
    bf16x8 aw = *(const bf16x8*)(wob + (size_t)orow * 256 + c0 + lg * 8);
#pragma unroll
    for (int nt = 0; nt < 4; ++nt) {
      bf16x8 bx = *(const bf16x8*)(Ot + ((size_t)b * HWN + pt * 64 + nt * 16 + ln) * 256 + c0 + lg * 8);
      acc[nt] = MFMA16(aw, bx, acc[nt]);
    }
  }
  float gm = gamma[0];
  int md = mode[0];
#pragma unroll
  for (int nt = 0; nt < 4; ++nt)
#pragma unroll
    for (int r = 0; r < 4; ++r) {
      int o = ot * 64 + w * 16 + lg * 4 + r;
      int p = pt * 64 + nt * 16 + ln;
      size_t off = ((size_t)b * 256 + o) * HWN + p;
      float v = acc[nt][r] + out_b[o];
      out[off] = (md == 0) ? (gm * v + x[off]) : v;
    }
}

// ---------------------------------------------------------------------------
extern "C" void kernel_launch(void* const* d_in, const int* in_sizes, int n_in,
                              void* d_out, int out_size, void* d_ws, size_t ws_size,
                              hipStream_t stream) {
  (void)in_sizes; (void)n_in; (void)out_size;
  const float* x     = (const float*)d_in[0];
  const float* qkv_w = (const float*)d_in[1];
  const float* qkv_b = (const float*)d_in[2];
  const float* out_w = (const float*)d_in[3];
  const float* out_b = (const float*)d_in[4];
  const float* gamma = (const float*)d_in[5];
  const int*   mode  = (const int*)d_in[6];
  float* out = (float*)d_out;

  char* wsb = (char*)d_ws;
  size_t off = 0;
  auto alloc = [&](size_t bytes) { char* p = wsb + off; off += bytes; return p; };
  unsigned short* xbT  = (unsigned short*)alloc(16777216);  // [2][16384][256]
  unsigned short* wqb  = (unsigned short*)alloc(196608);
  unsigned short* wob  = (unsigned short*)alloc(131072);
  unsigned short* qkvb = (unsigned short*)alloc(25165824);  // [2][384][16384]
  unsigned short* kT   = (unsigned short*)alloc(4194304);   // [4][16384][32]
  unsigned short* qpb  = (unsigned short*)alloc(262144);    // [4][32][1024]
  unsigned short* kpt  = (unsigned short*)alloc(262144);    // [4][1024][32]
  unsigned short* Eut  = (unsigned short*)alloc(8388608);   // [4][1024 j][1024 i]
  float*          lpart= (float*)alloc(65536);              // [4][4][1024]
  float*          linv = (float*)alloc(16384);              // [4][1024]
  float*          rvec = (float*)alloc(16384);              // [4][1024]
  float*          pacc = (float*)alloc(16777216);           // [4][16][8][128][64]
  float*          pl   = (float*)alloc(131072);             // [4][16][8][64]
  float*          Yf   = (float*)alloc(2097152);            // [4][128][1024] (-> W2f)
  unsigned short* U0b  = (unsigned short*)alloc(1048576);
  unsigned short* Va   = (unsigned short*)alloc(1048576);
  unsigned short* Vb   = (unsigned short*)alloc(1048576);
  unsigned short* W2b  = (unsigned short*)alloc(1048576);
  unsigned short* Ot   = (unsigned short*)pacc;             // alias: pacc dead after k_combine
  if (ws_size < off) return;   // ~78 MB

  k_cast<<<2208, 256, 0, stream>>>(x, qkv_w, out_w, xbT, wqb, wob);
  k_qkv<<<dim3(256, 6, 2), 256, 0, stream>>>(wqb, xbT, qkv_b, qkvb, kT);
  k_pool<<<512, 256, 0, stream>>>(qkvb, qpb, kpt);
  k_score<<<dim3(16, 4, 4), 256, 0, stream>>>(qpb, kpt, Eut, lpart);
  k_rvec<<<dim3(16, 4), 256, 0, stream>>>(Eut, lpart, linv, rvec);
  k_flashW1<<<dim3(16, 8, 4), 256, 0, stream>>>(qkvb, kT, qpb, pacc, pl);
  k_combine<<<2048, 256, 0, stream>>>(pacc, pl, Yf);
  k_proj<<<dim3(16, 4), 256, 0, stream>>>(rvec, Yf, U0b);
  k_neu<<<dim3(32, 2, 4), 256, 0, stream>>>(U0b, Eut, linv, Yf, Va, W2b, -1.f, 0);
  k_neu<<<dim3(32, 2, 4), 256, 0, stream>>>(Va,  Eut, linv, Yf, Vb, W2b, +1.f, 0);
  k_neu<<<dim3(32, 2, 4), 256, 0, stream>>>(Vb,  Eut, linv, Yf, Va, W2b, -1.f, 1);
  k_flashO<<<dim3(256, 4), 256, 0, stream>>>(qkvb, kpt, W2b, Ot);
  k_out<<<dim3(256, 4, 2), 256, 0, stream>>>(wob, Ot, out_b, x, gamma, mode, out);
}

// Round 5
// 311.927 us; speedup vs baseline: 11.5002x; 1.1850x over previous
//
#include <hip/hip_runtime.h>
#include <cstdint>
#include <cstddef>

#define HWN 16384   // H*W
#define NP1 1024    // pooled positions
#define RL2E 1.44269504f

typedef __attribute__((ext_vector_type(8))) short bf16x8;            // MFMA A/B frag
typedef __attribute__((ext_vector_type(8))) unsigned short ushort8v;
typedef __attribute__((ext_vector_type(4))) unsigned short ushort4v;
typedef __attribute__((ext_vector_type(2))) unsigned int uint2v;
typedef __attribute__((ext_vector_type(4))) unsigned int uint4v;
typedef __attribute__((ext_vector_type(4))) float f32x4;

__device__ __forceinline__ unsigned short f2bu(float f) {
  unsigned int u = __builtin_bit_cast(unsigned int, f);
  u = (u + 0x7FFFu + ((u >> 16) & 1u)) >> 16;   // RNE
  return (unsigned short)u;
}
__device__ __forceinline__ float b2f(unsigned short s) {
  unsigned int u = ((unsigned int)s) << 16;
  return __builtin_bit_cast(float, u);
}
// HW packed f32->bf16 (RNE): D.lo = bf16(S0), D.hi = bf16(S1)
__device__ __forceinline__ unsigned cvtpk(float lo, float hi) {
  unsigned r;
  asm("v_cvt_pk_bf16_f32 %0, %1, %2" : "=v"(r) : "v"(lo), "v"(hi));
  return r;
}
__device__ __forceinline__ bf16x8 scale_l2e(ushort8v t) {   // q-frag prescale by log2(e)
  ushort8v o;
#pragma unroll
  for (int q = 0; q < 8; ++q) o[q] = f2bu(RL2E * b2f(t[q]));
  return __builtin_bit_cast(bf16x8, o);
}
#define MFMA16(A,B,C) __builtin_amdgcn_mfma_f32_16x16x32_bf16((A),(B),(C),0,0,0)
// XOR-swizzled index (ushort units) for the 64x64 bf16 P tile: byte ^= (row&7)<<4
#define PIDX(r,c) ((((r) << 6) + (c)) ^ (((r) & 7) << 3))

// ---------------------------------------------------------------------------
// K0: cast+transpose x -> xbT[b][p][c] bf16 ; cast weights -> wqb, wob bf16
// ---------------------------------------------------------------------------
__global__ __launch_bounds__(256) void k_cast(
    const float* __restrict__ x, const float* __restrict__ qkv_w,
    const float* __restrict__ out_w, unsigned short* __restrict__ xbT,
    unsigned short* __restrict__ wqb, unsigned short* __restrict__ wob) {
  int bid = blockIdx.x, t = threadIdx.x;
  if (bid < 2048) {
    __shared__ float Lt[64][65];
    int b = bid >> 10, rest = bid & 1023, ct = rest >> 8, pt = rest & 255;
    const float* xp = x + ((size_t)b * 256 + ct * 64) * HWN + pt * 64;
    for (int it = 0; it < 16; ++it) {
      int idx = it * 256 + t; int cc = idx >> 6, pp = idx & 63;
      Lt[cc][pp] = xp[(size_t)cc * HWN + pp];
    }
    __syncthreads();
    int prow = t >> 2, c0 = (t & 3) * 16;
    unsigned short* dst = xbT + ((size_t)b * HWN + pt * 64 + prow) * 256 + ct * 64 + c0;
    uint4v o1, o2;
#pragma unroll
    for (int q = 0; q < 4; ++q) o1[q] = cvtpk(Lt[c0 + 2*q][prow], Lt[c0 + 2*q + 1][prow]);
#pragma unroll
    for (int q = 0; q < 4; ++q) o2[q] = cvtpk(Lt[c0 + 8 + 2*q][prow], Lt[c0 + 9 + 2*q][prow]);
    *(uint4v*)dst = o1;
    *(uint4v*)(dst + 8) = o2;
  } else {
    int base = (bid - 2048) * 1024 + t * 4;
    if (base < 98304) {
      float4 v = *(const float4*)(qkv_w + base);
      uint2v o; o[0] = cvtpk(v.x, v.y); o[1] = cvtpk(v.z, v.w);
      *(uint2v*)(wqb + base) = o;
    } else {
      int b2 = base - 98304;
      float4 v = *(const float4*)(out_w + b2);
      uint2v o; o[0] = cvtpk(v.x, v.y); o[1] = cvtpk(v.z, v.w);
      *(uint2v*)(wob + b2) = o;
    }
  }
}

// ---------------------------------------------------------------------------
// K1: qkv[b][o][p] = sum_c wqb[o][c]*xbT[p][c] + bias (MFMA) -> qkvb bf16
//     also writes kT[bg][p][32] (K channels transposed) when ot==1
// ---------------------------------------------------------------------------
__global__ __launch_bounds__(256) void k_qkv(
    const unsigned short* __restrict__ wqb, const unsigned short* __restrict__ xbT,
    const float* __restrict__ qkv_b, unsigned short* __restrict__ qkvb,
    unsigned short* __restrict__ kT) {
  int pt = blockIdx.x, ot = blockIdx.y, b = blockIdx.z;
  int tid = threadIdx.x, w = tid >> 6, lane = tid & 63;
  int lg = lane >> 4, ln = lane & 15;
  f32x4 acc[4] = {};
  const int orow = ot * 64 + w * 16 + ln;
#pragma unroll
  for (int ks = 0; ks < 8; ++ks) {
    int c0 = ks * 32;
    bf16x8 aw = *(const bf16x8*)(wqb + (size_t)orow * 256 + c0 + lg * 8);
#pragma unroll
    for (int nt = 0; nt < 4; ++nt) {
      bf16x8 bx = *(const bf16x8*)(xbT + ((size_t)b * HWN + pt * 64 + nt * 16 + ln) * 256 + c0 + lg * 8);
      acc[nt] = MFMA16(aw, bx, acc[nt]);
    }
  }
  int ob = ot * 64 + w * 16 + lg * 4;
  float b0 = qkv_b[ob], b1 = qkv_b[ob + 1], b2 = qkv_b[ob + 2], b3 = qkv_b[ob + 3];
#pragma unroll
  for (int nt = 0; nt < 4; ++nt) {
    int p = pt * 64 + nt * 16 + ln;
    unsigned u01 = cvtpk(acc[nt][0] + b0, acc[nt][1] + b1);
    unsigned u23 = cvtpk(acc[nt][2] + b2, acc[nt][3] + b3);
    size_t qb = ((size_t)b * 384 + ob) * HWN + p;
    qkvb[qb]           = (unsigned short)u01;
    qkvb[qb + HWN]     = (unsigned short)(u01 >> 16);
    qkvb[qb + 2 * HWN] = (unsigned short)u23;
    qkvb[qb + 3 * HWN] = (unsigned short)(u23 >> 16);
    if (ot == 1) {   // K channels: g=w>>1, d=(w&1)*16+lg*4
      int bgi = b * 2 + (w >> 1);
      int d0 = (w & 1) * 16 + lg * 4;
      uint2v kv; kv[0] = u01; kv[1] = u23;
      *(uint2v*)(kT + ((size_t)bgi * HWN + p) * 32 + d0) = kv;
    }
  }
}

// ---------------------------------------------------------------------------
// K2: 4x4 avg pool -> qpb[bg][32 d][1024 i] bf16, kpt[bg][1024 i][32 d] bf16
// ---------------------------------------------------------------------------
__global__ __launch_bounds__(256) void k_pool(
    const unsigned short* __restrict__ qkvb, unsigned short* __restrict__ qpb,
    unsigned short* __restrict__ kpt) {
  int idx = blockIdx.x * 256 + threadIdx.x;   // 131072
  int i1 = idx & 1023, cc = (idx >> 10) & 31, bg = idx >> 15;
  int b = bg >> 1, g = bg & 1;
  int h1 = i1 >> 5, w1 = i1 & 31;
  const unsigned short* bq = qkvb + (size_t)(b * 384 + g * 32 + cc) * HWN;
  const unsigned short* bk = qkvb + (size_t)(b * 384 + 64 + g * 32 + cc) * HWN;
  float sq = 0.f, sk = 0.f;
#pragma unroll
  for (int sh = 0; sh < 4; ++sh) {
    int off = (h1 * 4 + sh) * 128 + w1 * 4;
    ushort4v vq = *(const ushort4v*)(bq + off);
    ushort4v vk = *(const ushort4v*)(bk + off);
#pragma unroll
    for (int e = 0; e < 4; ++e) { sq += b2f(vq[e]); sk += b2f(vk[e]); }
  }
  qpb[((size_t)bg * 32 + cc) * NP1 + i1] = f2bu(sq * 0.0625f);
  kpt[((size_t)bg * NP1 + i1) * 32 + cc] = f2bu(sk * 0.0625f);
}

// ---------------------------------------------------------------------------
// K3: scores of A_m, single pass: Eut[bg][j][i] = bf16(exp(k_i . q_j)),
//     lpart[bg][ic][j] = partial column sums (pre-rounding f32).
// grid (jt 16, ic 4, bg 4)
// ---------------------------------------------------------------------------
__global__ __launch_bounds__(256) void k_score(
    const unsigned short* __restrict__ qpb, const unsigned short* __restrict__ kpt,
    unsigned short* __restrict__ Eut, float* __restrict__ lpart) {
  int jt = blockIdx.x, ic = blockIdx.y, bg = blockIdx.z;
  int tid = threadIdx.x, w = tid >> 6, lane = tid & 63;
  int lg = lane >> 4, ln = lane & 15;
  __shared__ float redL[4][64];
  bf16x8 bq[4];
#pragma unroll
  for (int nt = 0; nt < 4; ++nt) {
    ushort8v t8;
#pragma unroll
    for (int jr = 0; jr < 8; ++jr)
      t8[jr] = qpb[((size_t)bg * 32 + lg * 8 + jr) * NP1 + jt * 64 + nt * 16 + ln];
    bq[nt] = scale_l2e(t8);
  }
  float lsum[4] = {0.f, 0.f, 0.f, 0.f};
  for (int chk = 0; chk < 4; ++chk) {
    int i0 = ic * 256 + chk * 64;
    bf16x8 ak = *(const bf16x8*)(kpt + ((size_t)bg * NP1 + i0 + w * 16 + ln) * 32 + lg * 8);
#pragma unroll
    for (int nt = 0; nt < 4; ++nt) {
      f32x4 z = {0.f, 0.f, 0.f, 0.f};
      f32x4 s = MFMA16(ak, bq[nt], z);
      float e0 = exp2f(s[0]), e1 = exp2f(s[1]), e2 = exp2f(s[2]), e3 = exp2f(s[3]);
      lsum[nt] += (e0 + e1) + (e2 + e3);
      int j = jt * 64 + nt * 16 + ln;
      int ib = i0 + w * 16 + lg * 4;
      uint2v pk;
      pk[0] = cvtpk(e0, e1);
      pk[1] = cvtpk(e2, e3);
      *(uint2v*)(Eut + ((size_t)bg * NP1 + j) * NP1 + ib) = pk;
    }
  }
#pragma unroll
  for (int nt = 0; nt < 4; ++nt) {
    float v = lsum[nt];
    v += __shfl_xor(v, 16); v += __shfl_xor(v, 32);
    if (lane < 16) redL[w][nt * 16 + lane] = v;
  }
  __syncthreads();
  if (tid < 64)
    lpart[((size_t)(bg * 4 + ic)) * NP1 + jt * 64 + tid] =
        redL[0][tid] + redL[1][tid] + redL[2][tid] + redL[3][tid];
}

// ---------------------------------------------------------------------------
// K3b: row-parallel rvec partials, fully coalesced.
// grid (jc 32, bg 4). Each block: rows [jc*32, jc*32+32) of Eut.
// Also computes+writes linv for its 32 rows (from lpart).
// rvecp[jc][bg][i] = sum_{j in chunk} Eut[j][i] * linv[j]
// ---------------------------------------------------------------------------
__global__ __launch_bounds__(256) void k_rvec2(
    const unsigned short* __restrict__ Eut, const float* __restrict__ lpart,
    float* __restrict__ linv, float* __restrict__ rvecp) {
  int jc = blockIdx.x, bg = blockIdx.y, t = threadIdx.x;
  __shared__ float linv_s[32];
  if (t < 32) {
    int j = jc * 32 + t;
    float l = lpart[((size_t)(bg * 4 + 0)) * NP1 + j] + lpart[((size_t)(bg * 4 + 1)) * NP1 + j] +
              lpart[((size_t)(bg * 4 + 2)) * NP1 + j] + lpart[((size_t)(bg * 4 + 3)) * NP1 + j];
    float inv = 1.f / l;
    linv_s[t] = inv;
    linv[(size_t)bg * NP1 + j] = inv;
  }
  __syncthreads();
  int i0 = t * 4;
  float a0 = 0.f, a1 = 0.f, a2 = 0.f, a3 = 0.f;
#pragma unroll 8
  for (int jj = 0; jj < 32; ++jj) {
    float li = linv_s[jj];
    ushort4v e4 = *(const ushort4v*)(Eut + ((size_t)bg * NP1 + jc * 32 + jj) * NP1 + i0);
    a0 += b2f(e4[0]) * li; a1 += b2f(e4[1]) * li;
    a2 += b2f(e4[2]) * li; a3 += b2f(e4[3]) * li;
  }
  float4 o = {a0, a1, a2, a3};
  *(float4*)(rvecp + ((size_t)(jc * 4 + bg)) * NP1 + i0) = o;
}

// ---------------------------------------------------------------------------
// K4: flash W1 = Vf @ exp(Kf^T q) (max-free), split-K 8 partials (MFMA)
// grid (jt 16, kc 8, bg 4); double-buffered P tile, 1 barrier/chunk
// ---------------------------------------------------------------------------
__global__ __launch_bounds__(256) void k_flashW1(
    const unsigned short* __restrict__ qkvb, const unsigned short* __restrict__ kT,
    const unsigned short* __restrict__ qpb,
    float* __restrict__ pacc, float* __restrict__ pl) {
  int jt = blockIdx.x, kc = blockIdx.y, bg = blockIdx.z;
  int b = bg >> 1, g = bg & 1;
  int tid = threadIdx.x, w = tid >> 6, lane = tid & 63;
  int lg = lane >> 4, ln = lane & 15;
  __shared__ unsigned short PtS[2][64 * 64];
  __shared__ float redL[4][64];
  const int Vch = b * 384 + 128 + g * 128;
  bf16x8 bq[4];
#pragma unroll
  for (int nt = 0; nt < 4; ++nt) {
    ushort8v t8;
#pragma unroll
    for (int jr = 0; jr < 8; ++jr)
      t8[jr] = qpb[((size_t)bg * 32 + lg * 8 + jr) * NP1 + jt * 64 + nt * 16 + ln];
    bq[nt] = scale_l2e(t8);
  }
  f32x4 acc[2][4] = {};
  float lsum[4] = {0.f, 0.f, 0.f, 0.f};
  for (int chk = 0; chk < 32; ++chk) {
    int i0 = kc * 2048 + chk * 64;
    unsigned short* Pb = PtS[chk & 1];
    bf16x8 ak = *(const bf16x8*)(kT + ((size_t)bg * HWN + i0 + w * 16 + ln) * 32 + lg * 8);
    float e[4][4];
#pragma unroll
    for (int nt = 0; nt < 4; ++nt) {
      f32x4 z = {0.f, 0.f, 0.f, 0.f};
      f32x4 s = MFMA16(ak, bq[nt], z);
#pragma unroll
      for (int r = 0; r < 4; ++r) e[nt][r] = exp2f(s[r]);
      lsum[nt] += (e[nt][0] + e[nt][1]) + (e[nt][2] + e[nt][3]);
    }
#pragma unroll
    for (int nt = 0; nt < 4; ++nt) {
      uint2v pk;
      pk[0] = cvtpk(e[nt][0], e[nt][1]);
      pk[1] = cvtpk(e[nt][2], e[nt][3]);
      *(uint2v*)&Pb[PIDX(nt * 16 + ln, w * 16 + lg * 4)] = pk;
    }
    __syncthreads();   // P visible (buffer alternation protects vs. overwrite)
#pragma unroll
    for (int ist = 0; ist < 2; ++ist) {
      bf16x8 bp[4];
#pragma unroll
      for (int nt = 0; nt < 4; ++nt)
        bp[nt] = *(const bf16x8*)&Pb[PIDX(nt * 16 + ln, ist * 32 + lg * 8)];
#pragma unroll
      for (int ct = 0; ct < 2; ++ct) {
        bf16x8 av = *(const bf16x8*)(qkvb + (size_t)(Vch + w * 32 + ct * 16 + ln) * HWN + i0 + ist * 32 + lg * 8);
#pragma unroll
        for (int nt = 0; nt < 4; ++nt)
          acc[ct][nt] = MFMA16(av, bp[nt], acc[ct][nt]);
      }
    }
  }
  size_t pb = (((size_t)bg * 16 + jt) * 8 + kc) * 8192;
#pragma unroll
  for (int ct = 0; ct < 2; ++ct)
#pragma unroll
    for (int nt = 0; nt < 4; ++nt)
#pragma unroll
      for (int r = 0; r < 4; ++r)
        pacc[pb + (size_t)(w * 32 + ct * 16 + lg * 4 + r) * 64 + nt * 16 + ln] = acc[ct][nt][r];
#pragma unroll
  for (int nt = 0; nt < 4; ++nt) {
    float v = lsum[nt];
    v += __shfl_xor(v, 16); v += __shfl_xor(v, 32);
    if (lane < 16) redL[w][nt * 16 + lane] = v;
  }
  __syncthreads();
  if (tid < 64)
    pl[(((size_t)bg * 16 + jt) * 8 + kc) * 64 + tid] =
        redL[0][tid] + redL[1][tid] + redL[2][tid] + redL[3][tid];
}

// ---------------------------------------------------------------------------
// K5: combine split-K partials -> Yf = W1 (f32)
// ---------------------------------------------------------------------------
__global__ __launch_bounds__(256) void k_combine(
    const float* __restrict__ pacc, const float* __restrict__ pl,
    float* __restrict__ Yf) {
  int gid = blockIdx.x * 256 + threadIdx.x;   // 524288
  int bg = gid >> 17, rem = gid & 131071;
  int c = rem >> 10, j = rem & 1023;
  int jt = j >> 6, jj = j & 63;
  float s = 0.f, l = 0.f;
#pragma unroll
  for (int kc = 0; kc < 8; ++kc) {
    size_t pb = ((size_t)bg * 16 + jt) * 8 + kc;
    s += pacc[pb * 8192 + c * 64 + jj];
    l += pl[pb * 64 + jj];
  }
  Yf[gid] = s / l;
}

// ---------------------------------------------------------------------------
// K5b: Perron deflation, parallel: c_row = (y.r)/(1.r);
//      Yf := Y - c/2 (f32, W2 accumulator), U0b := bf16(Y - c).
// grid (ct 16, bg 4): each block handles 8 rows; rvec summed from partials
// ---------------------------------------------------------------------------
__global__ __launch_bounds__(256) void k_proj(
    const float* __restrict__ rvecp, float* __restrict__ Yf,
    unsigned short* __restrict__ U0b) {
  int ct = blockIdx.x, bg = blockIdx.y, t = threadIdx.x;
  __shared__ float rs[1024];
  __shared__ float red[256];
  __shared__ float crow[8];
  __shared__ float sSs;
  for (int j = t; j < 1024; j += 256) {
    float s = 0.f;
#pragma unroll
    for (int p = 0; p < 32; ++p) s += rvecp[((size_t)(p * 4 + bg)) * NP1 + j];
    rs[j] = s;
  }
  __syncthreads();
  float p = rs[t] + rs[t + 256] + rs[t + 512] + rs[t + 768];
  red[t] = p; __syncthreads();
  for (int s = 128; s > 0; s >>= 1) {
    if (t < s) red[t] += red[t + s];
    __syncthreads();
  }
  if (t == 0) sSs = red[0];
  __syncthreads();
  int row = t >> 5, ln32 = t & 31;
  const float* yrow = Yf + ((size_t)(bg * 128 + ct * 8 + row)) * NP1;
  float a = 0.f;
  for (int j = ln32; j < 1024; j += 32) a += yrow[j] * rs[j];
#pragma unroll
  for (int m = 1; m <= 16; m <<= 1) a += __shfl_xor(a, m, 32);
  if (ln32 == 0) crow[row] = a / sSs;
  __syncthreads();
  for (int e = t; e < 8 * 1024; e += 256) {
    int rr = e >> 10, j = e & 1023;
    size_t o = ((size_t)(bg * 128 + ct * 8 + rr)) * NP1 + j;
    float y = Yf[o], cv = crow[rr];
    Yf[o] = y - 0.5f * cv;
    U0b[o] = f2bu(y - cv);
  }
}

// ---------------------------------------------------------------------------
// K6: series step: V' = (Vin . Eut)*linv[j];  W2f += sgn*V' ;
//     last: W2b = bf16(W2f + sgn*V').  grid (jt 32, ct 2, bg 4)
// ---------------------------------------------------------------------------
__global__ __launch_bounds__(256) void k_neu(
    const unsigned short* __restrict__ Vin, const unsigned short* __restrict__ Eut,
    const float* __restrict__ linv, float* __restrict__ W2f,
    unsigned short* __restrict__ Vout, unsigned short* __restrict__ W2b,
    float sgn, int last) {
  int jt = blockIdx.x, ct = blockIdx.y, bg = blockIdx.z;
  int tid = threadIdx.x, w = tid >> 6, lane = tid & 63;
  int lg = lane >> 4, ln = lane & 15;
  int j0 = jt * 32, c0 = ct * 64 + w * 16;
  f32x4 acc[2] = {};
  for (int ks = 0; ks < 32; ++ks) {
    int i0 = ks * 32;
    bf16x8 a = *(const bf16x8*)(Vin + ((size_t)(bg * 128) + c0 + ln) * NP1 + i0 + lg * 8);
#pragma unroll
    for (int nt = 0; nt < 2; ++nt) {
      bf16x8 bt = *(const bf16x8*)(Eut + ((size_t)bg * NP1 + j0 + nt * 16 + ln) * NP1 + i0 + lg * 8);
      acc[nt] = MFMA16(a, bt, acc[nt]);
    }
  }
#pragma unroll
  for (int nt = 0; nt < 2; ++nt) {
    int j = j0 + nt * 16 + ln;
    float li = linv[(size_t)bg * NP1 + j];
#pragma unroll
    for (int r = 0; r < 4; ++r) {
      size_t o = ((size_t)(bg * 128) + c0 + lg * 4 + r) * NP1 + j;
      float v = acc[nt][r] * li;
      if (last) W2b[o] = f2bu(W2f[o] + sgn * v);
      else { Vout[o] = f2bu(v); W2f[o] += sgn * v; }
    }
  }
}

// ---------------------------------------------------------------------------
// K7: flash O = W2 @ exp(k^T Qf)/l + W2[:,i1(j)]   (full M^-1 in W2)
// grid (jt 256, bg 4); double-buffered P tile; writes Ot[b][p][c] bf16
// ---------------------------------------------------------------------------
__global__ __launch_bounds__(256) void k_flashO(
    const unsigned short* __restrict__ qkvb, const unsigned short* __restrict__ kpt,
    const unsigned short* __restrict__ W2b, unsigned short* __restrict__ Ot) {
  int jt = blockIdx.x, bg = blockIdx.y;
  int b = bg >> 1, g = bg & 1;
  int tid = threadIdx.x, w = tid >> 6, lane = tid & 63;
  int lg = lane >> 4, ln = lane & 15;
  __shared__ unsigned short PtS[2][64 * 64];
  __shared__ float redL[4][64];
  __shared__ float smL[64];
  const int Qch = b * 384 + g * 32;
  bf16x8 bq[4];
#pragma unroll
  for (int nt = 0; nt < 4; ++nt) {
    ushort8v t8;
#pragma unroll
    for (int jr = 0; jr < 8; ++jr)
      t8[jr] = qkvb[(size_t)(Qch + lg * 8 + jr) * HWN + jt * 64 + nt * 16 + ln];
    bq[nt] = scale_l2e(t8);
  }
  f32x4 acc[2][4] = {};
  float lsum[4] = {0.f, 0.f, 0.f, 0.f};
  for (int chk = 0; chk < 16; ++chk) {
    int i0 = chk * 64;
    unsigned short* Pb = PtS[chk & 1];
    bf16x8 ak = *(const bf16x8*)(kpt + ((size_t)bg * NP1 + i0 + w * 16 + ln) * 32 + lg * 8);
    float e[4][4];
#pragma unroll
    for (int nt = 0; nt < 4; ++nt) {
      f32x4 z = {0.f, 0.f, 0.f, 0.f};
      f32x4 s = MFMA16(ak, bq[nt], z);
#pragma unroll
      for (int r = 0; r < 4; ++r) e[nt][r] = exp2f(s[r]);
      lsum[nt] += (e[nt][0] + e[nt][1]) + (e[nt][2] + e[nt][3]);
    }
#pragma unroll
    for (int nt = 0; nt < 4; ++nt) {
      uint2v pk;
      pk[0] = cvtpk(e[nt][0], e[nt][1]);
      pk[1] = cvtpk(e[nt][2], e[nt][3]);
      *(uint2v*)&Pb[PIDX(nt * 16 + ln, w * 16 + lg * 4)] = pk;
    }
    __syncthreads();
#pragma unroll
    for (int ist = 0; ist < 2; ++ist) {
      bf16x8 bp[4];
#pragma unroll
      for (int nt = 0; nt < 4; ++nt)
        bp[nt] = *(const bf16x8*)&Pb[PIDX(nt * 16 + ln, ist * 32 + lg * 8)];
#pragma unroll
      for (int ct = 0; ct < 2; ++ct) {
        bf16x8 av = *(const bf16x8*)(W2b + ((size_t)bg * 128 + w * 32 + ct * 16 + ln) * NP1 + i0 + ist * 32 + lg * 8);
#pragma unroll
        for (int nt = 0; nt < 4; ++nt)
          acc[ct][nt] = MFMA16(av, bp[nt], acc[ct][nt]);
      }
    }
  }
#pragma unroll
  for (int nt = 0; nt < 4; ++nt) {
    float v = lsum[nt];
    v += __shfl_xor(v, 16); v += __shfl_xor(v, 32);
    if (lane < 16) redL[w][nt * 16 + lane] = v;
  }
  __syncthreads();
  if (tid < 64) smL[tid] = redL[0][tid] + redL[1][tid] + redL[2][tid] + redL[3][tid];
  __syncthreads();
#pragma unroll
  for (int nt = 0; nt < 4; ++nt) {
    int jj = nt * 16 + ln;
    int jg = jt * 64 + jj;
    float li = 1.f / smL[jj];
    int i1 = (jg >> 9) * 32 + ((jg & 127) >> 2);
#pragma unroll
    for (int ct = 0; ct < 2; ++ct) {
      int c = w * 32 + ct * 16 + lg * 4;
      float v0 = acc[ct][nt][0] * li + b2f(W2b[((size_t)bg * 128 + c + 0) * NP1 + i1]);
      float v1 = acc[ct][nt][1] * li + b2f(W2b[((size_t)bg * 128 + c + 1) * NP1 + i1]);
      float v2 = acc[ct][nt][2] * li + b2f(W2b[((size_t)bg * 128 + c + 2) * NP1 + i1]);
      float v3 = acc[ct][nt][3] * li + b2f(W2b[((size_t)bg * 128 + c + 3) * NP1 + i1]);
      uint2v o2; o2[0] = cvtpk(v0, v1); o2[1] = cvtpk(v2, v3);
      *(uint2v*)(Ot + ((size_t)b * HWN + jg) * 256 + g * 128 + c) = o2;
    }
  }
}

// ---------------------------------------------------------------------------
// K8: out = gamma * (wob @ Ot + out_b) + x  (MFMA, f32 epilogue)
// ---------------------------------------------------------------------------
__global__ __launch_bounds__(256) void k_out(
    const unsigned short* __restrict__ wob, const unsigned short* __restrict__ Ot,
    const float* __restrict__ out_b, const float* __restrict__ x,
    const float* __restrict__ gamma, const int* __restrict__ mode,
    float* __restrict__ out) {
  int pt = blockIdx.x, ot = blockIdx.y, b = blockIdx.z;
  int tid = threadIdx.x, w = tid >> 6, lane = tid & 63;
  int lg = lane >> 4, ln = lane & 15;
  f32x4 acc[4] = {};
  const int orow = ot * 64 + w * 16 + ln;
#pragma unroll
  for (int ks = 0; ks < 8; ++ks) {
    int c0 = ks * 32;
    bf16x8 aw = *(const bf16x8*)(wob + (size_t)orow * 256 + c0 + lg * 8);
#pragma unroll
    for (int nt = 0; nt < 4; ++nt) {
      bf16x8 bx = *(const bf16x8*)(Ot + ((size_t)b * HWN + pt * 64 + nt * 16 + ln) * 256 + c0 + lg * 8);
      acc[nt] = MFMA16(aw, bx, acc[nt]);
    }
  }
  float gm = gamma[0];
  int md = mode[0];
#pragma unroll
  for (int nt = 0; nt < 4; ++nt)
#pragma unroll
    for (int r = 0; r < 4; ++r) {
      int o = ot * 64 + w * 16 + lg * 4 + r;
      int p = pt * 64 + nt * 16 + ln;
      size_t off = ((size_t)b * 256 + o) * HWN + p;
      float v = acc[nt][r] + out_b[o];
      out[off] = (md == 0) ? (gm * v + x[off]) : v;
    }
}

// ---------------------------------------------------------------------------
extern "C" void kernel_launch(void* const* d_in, const int* in_sizes, int n_in,
                              void* d_out, int out_size, void* d_ws, size_t ws_size,
                              hipStream_t stream) {
  (void)in_sizes; (void)n_in; (void)out_size;
  const float* x     = (const float*)d_in[0];
  const float* qkv_w = (const float*)d_in[1];
  const float* qkv_b = (const float*)d_in[2];
  const float* out_w = (const float*)d_in[3];
  const float* out_b = (const float*)d_in[4];
  const float* gamma = (const float*)d_in[5];
  const int*   mode  = (const int*)d_in[6];
  float* out = (float*)d_out;

  char* wsb = (char*)d_ws;
  size_t off = 0;
  auto alloc = [&](size_t bytes) { char* p = wsb + off; off += bytes; return p; };
  unsigned short* xbT  = (unsigned short*)alloc(16777216);  // [2][16384][256]
  unsigned short* wqb  = (unsigned short*)alloc(196608);
  unsigned short* wob  = (unsigned short*)alloc(131072);
  unsigned short* qkvb = (unsigned short*)alloc(25165824);  // [2][384][16384]
  unsigned short* kT   = (unsigned short*)alloc(4194304);   // [4][16384][32]
  unsigned short* qpb  = (unsigned short*)alloc(262144);    // [4][32][1024]
  unsigned short* kpt  = (unsigned short*)alloc(262144);    // [4][1024][32]
  unsigned short* Eut  = (unsigned short*)alloc(8388608);   // [4][1024 j][1024 i]
  float*          lpart= (float*)alloc(65536);              // [4][4][1024]
  float*          linv = (float*)alloc(16384);              // [4][1024]
  float*          rvecp= (float*)alloc(524288);             // [32][4][1024]
  float*          pacc = (float*)alloc(16777216);           // [4][16][8][128][64]
  float*          pl   = (float*)alloc(131072);             // [4][16][8][64]
  float*          Yf   = (float*)alloc(2097152);            // [4][128][1024] (-> W2f)
  unsigned short* U0b  = (unsigned short*)alloc(1048576);
  unsigned short* Va   = (unsigned short*)alloc(1048576);
  unsigned short* Vb   = (unsigned short*)alloc(1048576);
  unsigned short* W2b  = (unsigned short*)alloc(1048576);
  unsigned short* Ot   = (unsigned short*)pacc;             // alias: pacc dead after k_combine
  if (ws_size < off) return;   // ~78.5 MB

  k_cast<<<2208, 256, 0, stream>>>(x, qkv_w, out_w, xbT, wqb, wob);
  k_qkv<<<dim3(256, 6, 2), 256, 0, stream>>>(wqb, xbT, qkv_b, qkvb, kT);
  k_pool<<<512, 256, 0, stream>>>(qkvb, qpb, kpt);
  k_score<<<dim3(16, 4, 4), 256, 0, stream>>>(qpb, kpt, Eut, lpart);
  k_rvec2<<<dim3(32, 4), 256, 0, stream>>>(Eut, lpart, linv, rvecp);
  k_flashW1<<<dim3(16, 8, 4), 256, 0, stream>>>(qkvb, kT, qpb, pacc, pl);
  k_combine<<<2048, 256, 0, stream>>>(pacc, pl, Yf);
  k_proj<<<dim3(16, 4), 256, 0, stream>>>(rvecp, Yf, U0b);
  k_neu<<<dim3(32, 2, 4), 256, 0, stream>>>(U0b, Eut, linv, Yf, Va, W2b, -1.f, 0);
  k_neu<<<dim3(32, 2, 4), 256, 0, stream>>>(Va,  Eut, linv, Yf, Vb, W2b, +1.f, 0);
  k_neu<<<dim3(32, 2, 4), 256, 0, stream>>>(Vb,  Eut, linv, Yf, Va, W2b, -1.f, 1);
  k_flashO<<<dim3(256, 4), 256, 0, stream>>>(qkvb, kpt, W2b, Ot);
  k_out<<<dim3(256, 4, 2), 256, 0, stream>>>(wob, Ot, out_b, x, gamma, mode, out);
}